// Round 3
// baseline (1382.922 us; speedup 1.0000x reference)
//
#include <hip/hip_runtime.h>

typedef unsigned short u16;
typedef unsigned int   u32;
typedef __bf16 bf16_t;
typedef bf16_t bf16x8 __attribute__((ext_vector_type(8)));
typedef float  floatx4 __attribute__((ext_vector_type(4)));

#define B_    2
#define QS    1024
#define HID_  2048
#define NH_   32
#define NKV_  8
#define HD_   64
#define KBN_  512
#define TOPK_ 100

__device__ __forceinline__ float b2f(u16 u) {
  union { u32 i; float f; } x; x.i = ((u32)u) << 16; return x.f;
}
__device__ __forceinline__ u16 f2b(float f) {
  union { float f; u32 i; } x; x.f = f;
  u32 r = x.i + 0x7fffu + ((x.i >> 16) & 1u);
  return (u16)(r >> 16);
}

// ---------------- f32 -> bf16 cast (vectorized: 4 elems/thread) ----------------
__global__ __launch_bounds__(256)
void cast_f2b(const float* __restrict__ x, u16* __restrict__ y, int n4) {
  int i = blockIdx.x * 256 + threadIdx.x;
  if (i >= n4) return;
  float4 v = ((const float4*)x)[i];
  ((uint2*)y)[i] = make_uint2((u32)f2b(v.x) | ((u32)f2b(v.y) << 16),
                              (u32)f2b(v.z) | ((u32)f2b(v.w) << 16));
}

// ---------------- transpose+cast: WT[n*K+k] = bf16(W[k*N+n]), W is f32 ----------------
__global__ __launch_bounds__(256)
void transpose_cast_k(const float* __restrict__ W, u16* __restrict__ WT, int K, int N) {
  __shared__ float tile[32][33];
  int n0 = blockIdx.x * 32, k0 = blockIdx.y * 32;
  int tx = threadIdx.x & 31, ty = threadIdx.x >> 5;  // 32 x 8
#pragma unroll
  for (int i = 0; i < 32; i += 8)
    tile[ty + i][tx] = W[(size_t)(k0 + ty + i) * N + n0 + tx];
  __syncthreads();
#pragma unroll
  for (int i = 0; i < 32; i += 8)
    WT[(size_t)(n0 + ty + i) * K + k0 + tx] = f2b(tile[tx][ty + i]);
}

// ---------------- GEMM: C[M,N] = A[M,K] * B[K,N], BT is N x K (bf16 in) ----------------
// 128x64 tile, 4 waves, each wave: 32 rows x 64 cols, K-step 32.
template <bool OUTF32>
__global__ __launch_bounds__(256)
void gemm_nt(const u16* __restrict__ A, const u16* __restrict__ BT,
             void* __restrict__ Cv, int M, int N, int K) {
  __shared__ __align__(16) u16 asf[8 * 64 * 8];  // 8 row-blocks in fragment order
  __shared__ __align__(16) u16 bsf[4 * 64 * 8];  // 4 col-blocks in fragment order
  int t = threadIdx.x;
  int lane = t & 63, w = t >> 6;
  int m0 = blockIdx.y * 128, n0 = blockIdx.x * 64;
  int fr = lane & 15;        // fragment non-K index
  int ko = (lane >> 4) * 8;  // K offset within 32-tile
  const u16* Ap0 = A + (size_t)(m0 + w * 16 + fr) * K + ko;
  const u16* Ap1 = A + (size_t)(m0 + (w + 4) * 16 + fr) * K + ko;
  const u16* Bp  = BT + (size_t)(n0 + w * 16 + fr) * K + ko;
  u16* as0 = &asf[(w * 64 + lane) * 8];
  u16* as1 = &asf[((w + 4) * 64 + lane) * 8];
  u16* bs0 = &bsf[(w * 64 + lane) * 8];
  floatx4 acc0[4], acc1[4];
#pragma unroll
  for (int c = 0; c < 4; ++c) {
    acc0[c] = (floatx4){0.f, 0.f, 0.f, 0.f};
    acc1[c] = (floatx4){0.f, 0.f, 0.f, 0.f};
  }
  for (int k0 = 0; k0 < K; k0 += 32) {
    __syncthreads();
    *(uint4*)as0 = *(const uint4*)(Ap0 + k0);
    *(uint4*)as1 = *(const uint4*)(Ap1 + k0);
    *(uint4*)bs0 = *(const uint4*)(Bp + k0);
    __syncthreads();
    bf16x8 a0 = *(bf16x8*)&asf[((2 * w) * 64 + lane) * 8];
    bf16x8 a1 = *(bf16x8*)&asf[((2 * w + 1) * 64 + lane) * 8];
#pragma unroll
    for (int c = 0; c < 4; ++c) {
      bf16x8 bb = *(bf16x8*)&bsf[(c * 64 + lane) * 8];
      acc0[c] = __builtin_amdgcn_mfma_f32_16x16x32_bf16(a0, bb, acc0[c], 0, 0, 0);
      acc1[c] = __builtin_amdgcn_mfma_f32_16x16x32_bf16(a1, bb, acc1[c], 0, 0, 0);
    }
  }
  int orow = (lane >> 4) * 4, ocol = lane & 15;
#pragma unroll
  for (int c = 0; c < 4; ++c)
#pragma unroll
    for (int r = 0; r < 4; ++r) {
      size_t i0 = (size_t)(m0 + 32 * w + orow + r) * N + n0 + 16 * c + ocol;
      size_t i1 = (size_t)(m0 + 32 * w + 16 + orow + r) * N + n0 + 16 * c + ocol;
      if constexpr (OUTF32) {
        ((float*)Cv)[i0] = acc0[c][r];
        ((float*)Cv)[i1] = acc1[c][r];
      } else {
        ((u16*)Cv)[i0] = f2b(acc0[c][r]);
        ((u16*)Cv)[i1] = f2b(acc1[c][r]);
      }
    }
}

// ---------------- RoPE (in place on bf16), cos/sin are f32 [Q,64] ----------------
__global__ __launch_bounds__(256)
void rope_k(u16* __restrict__ x, const float* __restrict__ ct, const float* __restrict__ st,
            const int* __restrict__ pid, int nh, int total) {
  int gid = blockIdx.x * 256 + threadIdx.x;
  if (gid >= total) return;
  int per_row = nh * 32;
  int row = gid / per_row;
  int rem = gid - row * per_row;
  int h = rem >> 5, d = rem & 31;
  int pos = pid[row];
  float c = ct[pos * 64 + d];
  float s = st[pos * 64 + d];
  size_t base = (size_t)row * (nh * 64) + h * 64 + d;
  float x0 = b2f(x[base]), x1 = b2f(x[base + 32]);
  x[base]      = f2b(x0 * c - x1 * s);
  x[base + 32] = f2b(x1 * c + x0 * s);
}

// ======== high-precision selection path (f32 inputs, double accumulate) ========
// hssum[b][c] = sum_q hs[b][q][c]
__global__ __launch_bounds__(256)
void hssum_k(const float* __restrict__ hs, double* __restrict__ hssum) {
  int b = blockIdx.x >> 3;
  int c = (blockIdx.x & 7) * 256 + threadIdx.x;
  double a = 0.0;
  for (int q = 0; q < QS; ++q) a += (double)hs[(size_t)(b * QS + q) * HID_ + c];
  hssum[b * HID_ + c] = a;
}

// S[b][g*64+d] = sum_c hssum[b][c] * sum_{m<4} Wqn[c][g*256+m*64+d]
__global__ __launch_bounds__(512)
void selS_k(const double* __restrict__ hssum, const float* __restrict__ Wqn,
            double* __restrict__ S) {
  int b = blockIdx.x, j = threadIdx.x;  // j in [0,512)
  int g = j >> 6, d = j & 63;
  __shared__ double hsl[HID_];
  for (int i = threadIdx.x; i < HID_; i += 512) hsl[i] = hssum[b * HID_ + i];
  __syncthreads();
  double acc = 0.0;
  for (int c = 0; c < HID_; ++c) {
    const float* w = Wqn + (size_t)c * HID_ + g * 256 + d;
    acc += hsl[c] * ((double)w[0] + (double)w[64] + (double)w[128] + (double)w[192]);
  }
  S[b * 512 + j] = acc;
}

// U[b][c] = sum_{j<512} S[b][j] * Wkbk[c][j]
__global__ __launch_bounds__(256)
void selU_k(const double* __restrict__ S, const float* __restrict__ Wkbk,
            double* __restrict__ U) {
  int b = blockIdx.x >> 3;
  int c = (blockIdx.x & 7) * 256 + threadIdx.x;
  __shared__ double Ss[512];
  Ss[threadIdx.x] = S[b * 512 + threadIdx.x];
  Ss[threadIdx.x + 256] = S[b * 512 + 256 + threadIdx.x];
  __syncthreads();
  const float* row = Wkbk + (size_t)c * 512;
  double acc = 0.0;
  for (int j = 0; j < 512; j += 4) {
    float4 wv = *(const float4*)(row + j);
    acc += Ss[j] * (double)wv.x + Ss[j + 1] * (double)wv.y +
           Ss[j + 2] * (double)wv.z + Ss[j + 3] * (double)wv.w;
  }
  U[b * HID_ + c] = acc;
}

// sel[b][n] = sum_c kb[b][n][c] * U[b][c]
__global__ __launch_bounds__(256)
void self_k(const double* __restrict__ U, const float* __restrict__ kbin,
            float* __restrict__ sel) {
  int b = blockIdx.x >> 1;
  int n = (blockIdx.x & 1) * 256 + threadIdx.x;
  const float* row = kbin + (size_t)(b * KBN_ + n) * HID_;
  const double* u = U + b * HID_;
  double acc = 0.0;
  for (int c = 0; c < HID_; c += 4) {
    float4 kv = *(const float4*)(row + c);
    acc += u[c] * (double)kv.x + u[c + 1] * (double)kv.y +
           u[c + 2] * (double)kv.z + u[c + 3] * (double)kv.w;
  }
  sel[b * KBN_ + n] = (float)acc;
}

// ---------------- top-100 (set selection; order irrelevant downstream) ----------------
__global__ __launch_bounds__(256)
void topk_k(float* __restrict__ sel, int* __restrict__ idx) {
  int b = blockIdx.x, t = threadIdx.x;
  __shared__ float bv[256];
  __shared__ int   bi[256];
  for (int it = 0; it < TOPK_; ++it) {
    float best = -3e38f; int bidx = 0;
    for (int n = t; n < KBN_; n += 256) {
      float vv = sel[b * KBN_ + n];
      if (vv > best) { best = vv; bidx = n; }
    }
    bv[t] = best; bi[t] = bidx;
    __syncthreads();
    for (int s = 128; s > 0; s >>= 1) {
      if (t < s && bv[t + s] > bv[t]) { bv[t] = bv[t + s]; bi[t] = bi[t + s]; }
      __syncthreads();
    }
    if (t == 0) { idx[b * TOPK_ + it] = bi[0]; sel[b * KBN_ + bi[0]] = -3e38f; }
    __syncthreads();
  }
}

// ---------------- fused flash attention (KB tiles + causal tiles) ----------------
#define ROWS 32
__global__ __launch_bounds__(256)
void attn_k(const u16* __restrict__ q, const u16* __restrict__ k, const u16* __restrict__ v,
            const u16* __restrict__ kbq, const u16* __restrict__ kbk, const u16* __restrict__ kbv,
            const int* __restrict__ topidx, u16* __restrict__ ctx) {
  int qt = blockIdx.x, h = blockIdx.y, b = blockIdx.z;
  int g = h >> 2;
  int t = threadIdx.x;
  __shared__ __align__(16) float qs[ROWS][68];
  __shared__ __align__(16) float ks[64][68];
  __shared__ __align__(16) float vs[64][68];
  __shared__ __align__(16) float ps[ROWS][68];
  const float scale = 0.125f;          // 1/sqrt(64)
  const float LOGADJ = 1.6331544f;     // ln(512/100)
  int q0 = qt * ROWS;
  int rp = t >> 4;
  int r0 = 2 * rp, r1 = r0 + 1;
  int jj = t & 15;
  int dj = (t & 15) * 4;
  float m0 = -1e30f, m1 = -1e30f, l0 = 0.f, l1 = 0.f;
  float4 acc0 = make_float4(0.f, 0.f, 0.f, 0.f);
  float4 acc1 = make_float4(0.f, 0.f, 0.f, 0.f);

  {  // stage qs from kbq (scaled) for KB tiles
    int r = t >> 3, dc = (t & 7) * 8;
    const u16* src = kbq + (size_t)(b * QS + q0 + r) * HID_ + h * 64 + dc;
    uint4 pk = *(const uint4*)src;
    const u16* pu = (const u16*)&pk;
#pragma unroll
    for (int i = 0; i < 8; ++i) qs[r][dc + i] = scale * b2f(pu[i]);
  }

  int nct = (q0 + ROWS + 63) >> 6;  // causal key tiles
  int ntiles = 2 + nct;
  for (int tile = 0; tile < ntiles; ++tile) {
    __syncthreads();  // protects LDS from previous iteration's readers
    if (tile == 2) {  // switch qs to RoPE'd q for causal tiles
      int r = t >> 3, dc = (t & 7) * 8;
      const u16* src = q + (size_t)(b * QS + q0 + r) * HID_ + h * 64 + dc;
      uint4 pk = *(const uint4*)src;
      const u16* pu = (const u16*)&pk;
#pragma unroll
      for (int i = 0; i < 8; ++i) qs[r][dc + i] = scale * b2f(pu[i]);
    }
    {  // stage ks, vs: thread -> key j = t>>2, dims (t&3)*16 .. +16
      int j = t >> 2, dc = (t & 3) * 16;
      const u16 *sk, *sv;
      if (tile < 2) {
        int slot = tile * 64 + j;
        int n = topidx[b * TOPK_ + (slot < TOPK_ ? slot : TOPK_ - 1)];
        sk = kbk + (size_t)(b * KBN_ + n) * 512 + g * 64 + dc;
        sv = kbv + (size_t)(b * KBN_ + n) * 512 + g * 64 + dc;
      } else {
        int key = (tile - 2) * 64 + j;
        sk = k + (size_t)(b * QS + key) * 512 + g * 64 + dc;
        sv = v + (size_t)(b * QS + key) * 512 + g * 64 + dc;
      }
      uint4 ka = *(const uint4*)sk, kb2 = *(const uint4*)(sk + 8);
      uint4 va = *(const uint4*)sv, vb2 = *(const uint4*)(sv + 8);
      const u16* pa = (const u16*)&ka; const u16* pb = (const u16*)&kb2;
#pragma unroll
      for (int i = 0; i < 8; ++i) { ks[j][dc + i] = b2f(pa[i]); ks[j][dc + 8 + i] = b2f(pb[i]); }
      pa = (const u16*)&va; pb = (const u16*)&vb2;
#pragma unroll
      for (int i = 0; i < 8; ++i) { vs[j][dc + i] = b2f(pa[i]); vs[j][dc + 8 + i] = b2f(pb[i]); }
    }
    __syncthreads();
    {  // scores: 2 rows x 4 keys per thread
      float sc0[4] = {0.f, 0.f, 0.f, 0.f}, sc1[4] = {0.f, 0.f, 0.f, 0.f};
      const float4* qr0 = (const float4*)qs[r0];
      const float4* qr1 = (const float4*)qs[r1];
#pragma unroll 4
      for (int d4 = 0; d4 < 16; ++d4) {
        float4 a0 = qr0[d4], a1 = qr1[d4];
#pragma unroll
        for (int kk = 0; kk < 4; ++kk) {
          const float4 kv = *(const float4*)&ks[jj + 16 * kk][d4 * 4];
          sc0[kk] += a0.x * kv.x + a0.y * kv.y + a0.z * kv.z + a0.w * kv.w;
          sc1[kk] += a1.x * kv.x + a1.y * kv.y + a1.z * kv.z + a1.w * kv.w;
        }
      }
#pragma unroll
      for (int kk = 0; kk < 4; ++kk) {
        int j = jj + 16 * kk;
        float v0 = sc0[kk], v1 = sc1[kk];
        if (tile < 2) {
          int slot = tile * 64 + j;
          if (slot >= TOPK_) { v0 = -1e30f; v1 = -1e30f; }
          else { v0 += LOGADJ; v1 += LOGADJ; }
        } else {
          int key = (tile - 2) * 64 + j;
          if (key > q0 + r0) v0 = -1e30f;
          if (key > q0 + r1) v1 = -1e30f;
        }
        ps[r0][j] = v0; ps[r1][j] = v1;
      }
    }
    __syncthreads();
    {  // online softmax + PV: same 2 rows, 4 dims per thread
      const float4* pr0 = (const float4*)ps[r0];
      const float4* pr1 = (const float4*)ps[r1];
      float tm0 = -1e30f, tm1 = -1e30f;
#pragma unroll 4
      for (int j4 = 0; j4 < 16; ++j4) {
        float4 a0 = pr0[j4], a1 = pr1[j4];
        tm0 = fmaxf(tm0, fmaxf(fmaxf(a0.x, a0.y), fmaxf(a0.z, a0.w)));
        tm1 = fmaxf(tm1, fmaxf(fmaxf(a1.x, a1.y), fmaxf(a1.z, a1.w)));
      }
      float mn0 = fmaxf(m0, tm0), mn1 = fmaxf(m1, tm1);
      float al0 = __expf(m0 - mn0), al1 = __expf(m1 - mn1);
      acc0.x *= al0; acc0.y *= al0; acc0.z *= al0; acc0.w *= al0;
      acc1.x *= al1; acc1.y *= al1; acc1.z *= al1; acc1.w *= al1;
      float sum0 = 0.f, sum1 = 0.f;
#pragma unroll 2
      for (int j4 = 0; j4 < 16; ++j4) {
        float4 p0 = pr0[j4], p1 = pr1[j4];
        float pe[4] = {p0.x, p0.y, p0.z, p0.w};
        float qe[4] = {p1.x, p1.y, p1.z, p1.w};
#pragma unroll
        for (int e = 0; e < 4; ++e) {
          const float4 vv = *(const float4*)&vs[j4 * 4 + e][dj];
          float e0 = __expf(pe[e] - mn0); sum0 += e0;
          float e1 = __expf(qe[e] - mn1); sum1 += e1;
          acc0.x += e0 * vv.x; acc0.y += e0 * vv.y; acc0.z += e0 * vv.z; acc0.w += e0 * vv.w;
          acc1.x += e1 * vv.x; acc1.y += e1 * vv.y; acc1.z += e1 * vv.z; acc1.w += e1 * vv.w;
        }
      }
      l0 = l0 * al0 + sum0; m0 = mn0;
      l1 = l1 * al1 + sum1; m1 = mn1;
    }
  }
  float i0 = 1.f / l0, i1 = 1.f / l1;
  size_t ob0 = (size_t)(b * QS + q0 + r0) * HID_ + h * 64 + dj;
  size_t ob1 = (size_t)(b * QS + q0 + r1) * HID_ + h * 64 + dj;
  ctx[ob0 + 0] = f2b(acc0.x * i0); ctx[ob0 + 1] = f2b(acc0.y * i0);
  ctx[ob0 + 2] = f2b(acc0.z * i0); ctx[ob0 + 3] = f2b(acc0.w * i0);
  ctx[ob1 + 0] = f2b(acc1.x * i1); ctx[ob1 + 1] = f2b(acc1.y * i1);
  ctx[ob1 + 2] = f2b(acc1.z * i1); ctx[ob1 + 3] = f2b(acc1.w * i1);
}

// ---------------- host ----------------
extern "C" void kernel_launch(void* const* d_in, const int* in_sizes, int n_in,
                              void* d_out, int out_size, void* d_ws, size_t ws_size,
                              hipStream_t stream) {
  (void)in_sizes; (void)n_in; (void)out_size; (void)ws_size;
  const float* hs_f = (const float*)d_in[0];
  const float* kb_f = (const float*)d_in[1];
  const float* Wq   = (const float*)d_in[2];
  const float* Wk   = (const float*)d_in[3];
  const float* Wv   = (const float*)d_in[4];
  const float* Wo   = (const float*)d_in[5];
  const float* Wqn  = (const float*)d_in[6];
  const float* Wkbk = (const float*)d_in[7];
  const float* Wkbv = (const float*)d_in[8];
  const float* cosT = (const float*)d_in[9];
  const float* sinT = (const float*)d_in[10];
  const int*   pid  = (const int*)d_in[12];
  float* out = (float*)d_out;

  char* p = (char*)d_ws;
  u16* WT     = (u16*)p; p += (size_t)2048 * 2048 * 2;
  u16* hs_b   = (u16*)p; p += (size_t)B_ * QS * HID_ * 2;
  u16* kb_b   = (u16*)p; p += (size_t)B_ * KBN_ * HID_ * 2;
  u16* q_ws   = (u16*)p; p += (size_t)B_ * QS * HID_ * 2;
  u16* kbq_ws = (u16*)p; p += (size_t)B_ * QS * HID_ * 2;
  u16* k_ws   = (u16*)p; p += (size_t)B_ * QS * 512 * 2;
  u16* v_ws   = (u16*)p; p += (size_t)B_ * QS * 512 * 2;
  u16* kbk_ws = (u16*)p; p += (size_t)B_ * KBN_ * 512 * 2;
  u16* kbv_ws = (u16*)p; p += (size_t)B_ * KBN_ * 512 * 2;
  u16* ctx_ws = (u16*)p; p += (size_t)B_ * QS * HID_ * 2;
  double* hssum_ws = (double*)p; p += (size_t)B_ * HID_ * 8;
  double* S_ws     = (double*)p; p += (size_t)B_ * 512 * 8;
  double* U_ws     = (double*)p; p += (size_t)B_ * HID_ * 8;
  float*  sel_ws   = (float*)p;  p += (size_t)B_ * KBN_ * 4;
  int*    idx_ws   = (int*)p;    p += (size_t)B_ * TOPK_ * 4;

  dim3 blk(256);
  // cast activations to bf16
  cast_f2b<<<dim3((B_ * QS * HID_ / 4 + 255) / 256), blk, 0, stream>>>(hs_f, hs_b, B_ * QS * HID_ / 4);
  cast_f2b<<<dim3((B_ * KBN_ * HID_ / 4 + 255) / 256), blk, 0, stream>>>(kb_f, kb_b, B_ * KBN_ * HID_ / 4);
  // q = hs @ Wq
  transpose_cast_k<<<dim3(64, 64), blk, 0, stream>>>(Wq, WT, 2048, 2048);
  gemm_nt<false><<<dim3(32, 16), blk, 0, stream>>>(hs_b, WT, q_ws, 2048, 2048, 2048);
  // kbq = hs @ Wq_new
  transpose_cast_k<<<dim3(64, 64), blk, 0, stream>>>(Wqn, WT, 2048, 2048);
  gemm_nt<false><<<dim3(32, 16), blk, 0, stream>>>(hs_b, WT, kbq_ws, 2048, 2048, 2048);
  // k = hs @ Wk
  transpose_cast_k<<<dim3(16, 64), blk, 0, stream>>>(Wk, WT, 2048, 512);
  gemm_nt<false><<<dim3(8, 16), blk, 0, stream>>>(hs_b, WT, k_ws, 2048, 512, 2048);
  // v = hs @ Wv
  transpose_cast_k<<<dim3(16, 64), blk, 0, stream>>>(Wv, WT, 2048, 512);
  gemm_nt<false><<<dim3(8, 16), blk, 0, stream>>>(hs_b, WT, v_ws, 2048, 512, 2048);
  // kbk = kb @ Wkb_k
  transpose_cast_k<<<dim3(16, 64), blk, 0, stream>>>(Wkbk, WT, 2048, 512);
  gemm_nt<false><<<dim3(8, 8), blk, 0, stream>>>(kb_b, WT, kbk_ws, 1024, 512, 2048);
  // kbv = kb @ Wkb_v
  transpose_cast_k<<<dim3(16, 64), blk, 0, stream>>>(Wkbv, WT, 2048, 512);
  gemm_nt<false><<<dim3(8, 8), blk, 0, stream>>>(kb_b, WT, kbv_ws, 1024, 512, 2048);
  // RoPE on q, k
  rope_k<<<dim3((B_ * QS * NH_ * 32) / 256), blk, 0, stream>>>(q_ws, cosT, sinT, pid, NH_, B_ * QS * NH_ * 32);
  rope_k<<<dim3((B_ * QS * NKV_ * 32) / 256), blk, 0, stream>>>(k_ws, cosT, sinT, pid, NKV_, B_ * QS * NKV_ * 32);
  // KB selection — high-precision path from original f32 inputs
  hssum_k<<<dim3(B_ * 8), blk, 0, stream>>>(hs_f, hssum_ws);
  selS_k<<<dim3(B_), dim3(512), 0, stream>>>(hssum_ws, Wqn, S_ws);
  selU_k<<<dim3(B_ * 8), blk, 0, stream>>>(S_ws, Wkbk, U_ws);
  self_k<<<dim3(B_ * 2), blk, 0, stream>>>(U_ws, kb_f, sel_ws);
  topk_k<<<dim3(B_), blk, 0, stream>>>(sel_ws, idx_ws);
  // fused attention
  attn_k<<<dim3(QS / ROWS, NH_, B_), blk, 0, stream>>>(q_ws, k_ws, v_ws, kbq_ws, kbk_ws, kbv_ws, idx_ws, ctx_ws);
  // out = ctx @ Wo  (f32 output)
  transpose_cast_k<<<dim3(64, 64), blk, 0, stream>>>(Wo, WT, 2048, 2048);
  gemm_nt<true><<<dim3(32, 16), blk, 0, stream>>>(ctx_ws, WT, out, 2048, 2048, 2048);
}

// Round 4
// 991.809 us; speedup vs baseline: 1.3943x; 1.3943x over previous
//
#include <hip/hip_runtime.h>

typedef unsigned short u16;
typedef unsigned int   u32;
typedef __bf16 bf16_t;
typedef bf16_t bf16x8 __attribute__((ext_vector_type(8)));
typedef float  floatx4 __attribute__((ext_vector_type(4)));

#define B_    2
#define QS    1024
#define HID_  2048
#define NH_   32
#define NKV_  8
#define HD_   64
#define KBN_  512
#define TOPK_ 100

__device__ __forceinline__ float b2f(u16 u) {
  union { u32 i; float f; } x; x.i = ((u32)u) << 16; return x.f;
}
__device__ __forceinline__ u16 f2b(float f) {
  union { float f; u32 i; } x; x.f = f;
  u32 r = x.i + 0x7fffu + ((x.i >> 16) & 1u);
  return (u16)(r >> 16);
}

// ---------------- f32 -> bf16 cast (vectorized: 4 elems/thread) ----------------
__global__ __launch_bounds__(256)
void cast_f2b(const float* __restrict__ x, u16* __restrict__ y, int n4) {
  int i = blockIdx.x * 256 + threadIdx.x;
  if (i >= n4) return;
  float4 v = ((const float4*)x)[i];
  ((uint2*)y)[i] = make_uint2((u32)f2b(v.x) | ((u32)f2b(v.y) << 16),
                              (u32)f2b(v.z) | ((u32)f2b(v.w) << 16));
}

// ---------------- transpose+cast: WT[n*K+k] = bf16(W[k*N+n]), W is f32 ----------------
__global__ __launch_bounds__(256)
void transpose_cast_k(const float* __restrict__ W, u16* __restrict__ WT, int K, int N) {
  __shared__ float tile[32][33];
  int n0 = blockIdx.x * 32, k0 = blockIdx.y * 32;
  int tx = threadIdx.x & 31, ty = threadIdx.x >> 5;  // 32 x 8
#pragma unroll
  for (int i = 0; i < 32; i += 8)
    tile[ty + i][tx] = W[(size_t)(k0 + ty + i) * N + n0 + tx];
  __syncthreads();
#pragma unroll
  for (int i = 0; i < 32; i += 8)
    WT[(size_t)(n0 + ty + i) * K + k0 + tx] = f2b(tile[tx][ty + i]);
}

// ---------------- GEMM: C[M,N] = A[M,K] * B[K,N], BT is N x K (bf16 in) ----------------
template <bool OUTF32>
__global__ __launch_bounds__(256)
void gemm_nt(const u16* __restrict__ A, const u16* __restrict__ BT,
             void* __restrict__ Cv, int M, int N, int K) {
  __shared__ __align__(16) u16 asf[8 * 64 * 8];
  __shared__ __align__(16) u16 bsf[4 * 64 * 8];
  int t = threadIdx.x;
  int lane = t & 63, w = t >> 6;
  int m0 = blockIdx.y * 128, n0 = blockIdx.x * 64;
  int fr = lane & 15;
  int ko = (lane >> 4) * 8;
  const u16* Ap0 = A + (size_t)(m0 + w * 16 + fr) * K + ko;
  const u16* Ap1 = A + (size_t)(m0 + (w + 4) * 16 + fr) * K + ko;
  const u16* Bp  = BT + (size_t)(n0 + w * 16 + fr) * K + ko;
  u16* as0 = &asf[(w * 64 + lane) * 8];
  u16* as1 = &asf[((w + 4) * 64 + lane) * 8];
  u16* bs0 = &bsf[(w * 64 + lane) * 8];
  floatx4 acc0[4], acc1[4];
#pragma unroll
  for (int c = 0; c < 4; ++c) {
    acc0[c] = (floatx4){0.f, 0.f, 0.f, 0.f};
    acc1[c] = (floatx4){0.f, 0.f, 0.f, 0.f};
  }
  for (int k0 = 0; k0 < K; k0 += 32) {
    __syncthreads();
    *(uint4*)as0 = *(const uint4*)(Ap0 + k0);
    *(uint4*)as1 = *(const uint4*)(Ap1 + k0);
    *(uint4*)bs0 = *(const uint4*)(Bp + k0);
    __syncthreads();
    bf16x8 a0 = *(bf16x8*)&asf[((2 * w) * 64 + lane) * 8];
    bf16x8 a1 = *(bf16x8*)&asf[((2 * w + 1) * 64 + lane) * 8];
#pragma unroll
    for (int c = 0; c < 4; ++c) {
      bf16x8 bb = *(bf16x8*)&bsf[(c * 64 + lane) * 8];
      acc0[c] = __builtin_amdgcn_mfma_f32_16x16x32_bf16(a0, bb, acc0[c], 0, 0, 0);
      acc1[c] = __builtin_amdgcn_mfma_f32_16x16x32_bf16(a1, bb, acc1[c], 0, 0, 0);
    }
  }
  int orow = (lane >> 4) * 4, ocol = lane & 15;
#pragma unroll
  for (int c = 0; c < 4; ++c)
#pragma unroll
    for (int r = 0; r < 4; ++r) {
      size_t i0 = (size_t)(m0 + 32 * w + orow + r) * N + n0 + 16 * c + ocol;
      size_t i1 = (size_t)(m0 + 32 * w + 16 + orow + r) * N + n0 + 16 * c + ocol;
      if constexpr (OUTF32) {
        ((float*)Cv)[i0] = acc0[c][r];
        ((float*)Cv)[i1] = acc1[c][r];
      } else {
        ((u16*)Cv)[i0] = f2b(acc0[c][r]);
        ((u16*)Cv)[i1] = f2b(acc1[c][r]);
      }
    }
}

// ---------------- RoPE (in place on bf16), cos/sin are f32 [Q,64] ----------------
__global__ __launch_bounds__(256)
void rope_k(u16* __restrict__ x, const float* __restrict__ ct, const float* __restrict__ st,
            const int* __restrict__ pid, int nh, int total) {
  int gid = blockIdx.x * 256 + threadIdx.x;
  if (gid >= total) return;
  int per_row = nh * 32;
  int row = gid / per_row;
  int rem = gid - row * per_row;
  int h = rem >> 5, d = rem & 31;
  int pos = pid[row];
  float c = ct[pos * 64 + d];
  float s = st[pos * 64 + d];
  size_t base = (size_t)row * (nh * 64) + h * 64 + d;
  float x0 = b2f(x[base]), x1 = b2f(x[base + 32]);
  x[base]      = f2b(x0 * c - x1 * s);
  x[base + 32] = f2b(x1 * c + x0 * s);
}

// ======== high-precision selection path (f32 inputs, double accumulate) ========
__global__ __launch_bounds__(256)
void hssum_k(const float* __restrict__ hs, double* __restrict__ hssum) {
  int b = blockIdx.x >> 3;
  int c = (blockIdx.x & 7) * 256 + threadIdx.x;
  double a = 0.0;
  for (int q = 0; q < QS; ++q) a += (double)hs[(size_t)(b * QS + q) * HID_ + c];
  hssum[b * HID_ + c] = a;
}

__global__ __launch_bounds__(512)
void selS_k(const double* __restrict__ hssum, const float* __restrict__ Wqn,
            double* __restrict__ S) {
  int b = blockIdx.x, j = threadIdx.x;  // j in [0,512)
  int g = j >> 6, d = j & 63;
  __shared__ double hsl[HID_];
  for (int i = threadIdx.x; i < HID_; i += 512) hsl[i] = hssum[b * HID_ + i];
  __syncthreads();
  double acc = 0.0;
  for (int c = 0; c < HID_; ++c) {
    const float* w = Wqn + (size_t)c * HID_ + g * 256 + d;
    acc += hsl[c] * ((double)w[0] + (double)w[64] + (double)w[128] + (double)w[192]);
  }
  S[b * 512 + j] = acc;
}

__global__ __launch_bounds__(256)
void selU_k(const double* __restrict__ S, const float* __restrict__ Wkbk,
            double* __restrict__ U) {
  int b = blockIdx.x >> 3;
  int c = (blockIdx.x & 7) * 256 + threadIdx.x;
  __shared__ double Ss[512];
  Ss[threadIdx.x] = S[b * 512 + threadIdx.x];
  Ss[threadIdx.x + 256] = S[b * 512 + 256 + threadIdx.x];
  __syncthreads();
  const float* row = Wkbk + (size_t)c * 512;
  double acc = 0.0;
  for (int j = 0; j < 512; j += 4) {
    float4 wv = *(const float4*)(row + j);
    acc += Ss[j] * (double)wv.x + Ss[j + 1] * (double)wv.y +
           Ss[j + 2] * (double)wv.z + Ss[j + 3] * (double)wv.w;
  }
  U[b * HID_ + c] = acc;
}

__global__ __launch_bounds__(256)
void self_k(const double* __restrict__ U, const float* __restrict__ kbin,
            float* __restrict__ sel) {
  int b = blockIdx.x >> 1;
  int n = (blockIdx.x & 1) * 256 + threadIdx.x;
  const float* row = kbin + (size_t)(b * KBN_ + n) * HID_;
  const double* u = U + b * HID_;
  double acc = 0.0;
  for (int c = 0; c < HID_; c += 4) {
    float4 kv = *(const float4*)(row + c);
    acc += u[c] * (double)kv.x + u[c + 1] * (double)kv.y +
           u[c + 2] * (double)kv.z + u[c + 3] * (double)kv.w;
  }
  sel[b * KBN_ + n] = (float)acc;
}

// ---------------- top-100 (set selection; order irrelevant downstream) ----------------
__global__ __launch_bounds__(256)
void topk_k(float* __restrict__ sel, int* __restrict__ idx) {
  int b = blockIdx.x, t = threadIdx.x;
  __shared__ float bv[256];
  __shared__ int   bi[256];
  for (int it = 0; it < TOPK_; ++it) {
    float best = -3e38f; int bidx = 0;
    for (int n = t; n < KBN_; n += 256) {
      float vv = sel[b * KBN_ + n];
      if (vv > best) { best = vv; bidx = n; }
    }
    bv[t] = best; bi[t] = bidx;
    __syncthreads();
    for (int s = 128; s > 0; s >>= 1) {
      if (t < s && bv[t + s] > bv[t]) { bv[t] = bv[t + s]; bi[t] = bi[t + s]; }
      __syncthreads();
    }
    if (t == 0) { idx[b * TOPK_ + it] = bi[0]; sel[b * KBN_ + bi[0]] = -3e38f; }
    __syncthreads();
  }
}

// ---------------- MFMA flash attention ----------------
// Block: 64 q-rows x (b,h). 4 waves x 16 rows. Key tiles of 64.
// Tiles 0,1 = KB slots 0..127 (>=100 masked); tiles 2.. = causal.
__global__ __launch_bounds__(256)
void attn_mfma_k(const u16* __restrict__ q, const u16* __restrict__ k, const u16* __restrict__ v,
                 const u16* __restrict__ kbq, const u16* __restrict__ kbk, const u16* __restrict__ kbv,
                 const int* __restrict__ topidx, u16* __restrict__ ctx) {
  int qt = blockIdx.x, h = blockIdx.y, b = blockIdx.z;
  int g = h >> 2;
  int t = threadIdx.x, lane = t & 63, w = t >> 6;
  int quad = lane >> 4, col = lane & 15;
  __shared__ __align__(16) u16 ks[64 * 72];      // [key][dim], pad 72 (144B stride)
  __shared__ __align__(16) u16 vst[64 * 64];     // [dim][key ^ ((dim&7)<<3)] swizzled
  __shared__ __align__(16) u16 ps[4][16 * 72];   // per-wave P tile [row][key]
  const float LOGADJ = 1.6331544f;               // ln(512/100)
  int q0 = qt * 64;

  // Q fragments in registers, pre-scaled by 1/8 (exact in bf16)
  int qrow_frag = q0 + w * 16 + col;
  bf16x8 aKB[2], aC[2];
#pragma unroll
  for (int kstep = 0; kstep < 2; ++kstep) {
    const u16* p1 = kbq + (size_t)(b * QS + qrow_frag) * HID_ + h * 64 + kstep * 32 + quad * 8;
    const u16* p2 = q   + (size_t)(b * QS + qrow_frag) * HID_ + h * 64 + kstep * 32 + quad * 8;
    uint4 x1 = *(const uint4*)p1, x2 = *(const uint4*)p2;
    const u16* u1 = (const u16*)&x1; const u16* u2 = (const u16*)&x2;
#pragma unroll
    for (int i = 0; i < 8; ++i) {
      aKB[kstep][i] = (bf16_t)(0.125f * b2f(u1[i]));
      aC[kstep][i]  = (bf16_t)(0.125f * b2f(u2[i]));
    }
  }

  float mrow[4] = {-1e30f, -1e30f, -1e30f, -1e30f};
  float lrow[4] = {0.f, 0.f, 0.f, 0.f};
  floatx4 acc[4];
#pragma unroll
  for (int nb = 0; nb < 4; ++nb) acc[nb] = (floatx4){0.f, 0.f, 0.f, 0.f};

  int ntiles = 2 + (q0 >> 6) + 1;
  for (int tile = 0; tile < ntiles; ++tile) {
    __syncthreads();
    {  // stage ks: thread -> key j=t>>2, dims (t&3)*16..+15
      int j = t >> 2, dc = (t & 3) * 16;
      const u16* src;
      if (tile < 2) {
        int slot = tile * 64 + j;
        int n = topidx[b * TOPK_ + (slot < TOPK_ ? slot : TOPK_ - 1)];
        src = kbk + (size_t)(b * KBN_ + n) * 512 + g * 64 + dc;
      } else {
        int key = (tile - 2) * 64 + j;
        src = k + (size_t)(b * QS + key) * 512 + g * 64 + dc;
      }
      *(uint4*)&ks[j * 72 + dc]     = *(const uint4*)src;
      *(uint4*)&ks[j * 72 + dc + 8] = *(const uint4*)(src + 8);
    }
    {  // stage vst transposed+swizzled: thread -> dim d=t&63, keys kc*16..+15
      int d = t & 63, kc = t >> 6;
      __align__(16) u16 tmp[16];
      if (tile < 2) {
#pragma unroll
        for (int i = 0; i < 16; ++i) {
          int slot = tile * 64 + kc * 16 + i;
          int n = topidx[b * TOPK_ + (slot < TOPK_ ? slot : TOPK_ - 1)];
          tmp[i] = kbv[(size_t)(b * KBN_ + n) * 512 + g * 64 + d];
        }
      } else {
        const u16* src = v + (size_t)(b * QS + (tile - 2) * 64 + kc * 16) * 512 + g * 64 + d;
#pragma unroll
        for (int i = 0; i < 16; ++i) tmp[i] = src[(size_t)i * 512];
      }
      int sw = d & 7;
      *(uint4*)&vst[d * 64 + ((2 * kc) ^ sw) * 8]     = *(uint4*)&tmp[0];
      *(uint4*)&vst[d * 64 + ((2 * kc + 1) ^ sw) * 8] = *(uint4*)&tmp[8];
    }
    __syncthreads();

    // ---- QK^T: scores s[nb] (16 rows x 16 keys per block nb) ----
    bf16x8 aq0 = (tile < 2) ? aKB[0] : aC[0];
    bf16x8 aq1 = (tile < 2) ? aKB[1] : aC[1];
    floatx4 s[4];
#pragma unroll
    for (int nb = 0; nb < 4; ++nb) {
      s[nb] = (floatx4){0.f, 0.f, 0.f, 0.f};
      bf16x8 b0 = *(bf16x8*)&ks[(nb * 16 + col) * 72 + quad * 8];
      bf16x8 b1 = *(bf16x8*)&ks[(nb * 16 + col) * 72 + 32 + quad * 8];
      s[nb] = __builtin_amdgcn_mfma_f32_16x16x32_bf16(aq0, b0, s[nb], 0, 0, 0);
      s[nb] = __builtin_amdgcn_mfma_f32_16x16x32_bf16(aq1, b1, s[nb], 0, 0, 0);
    }
    // ---- masks ----
    if (tile < 2) {
#pragma unroll
      for (int nb = 0; nb < 4; ++nb) {
        int slot = tile * 64 + nb * 16 + col;
        bool dead = (slot >= TOPK_);
#pragma unroll
        for (int rr = 0; rr < 4; ++rr)
          s[nb][rr] = dead ? -1e30f : (s[nb][rr] + LOGADJ);
      }
    } else {
      int kbase = (tile - 2) * 64;
#pragma unroll
      for (int nb = 0; nb < 4; ++nb) {
        int key = kbase + nb * 16 + col;
#pragma unroll
        for (int rr = 0; rr < 4; ++rr) {
          int qrow = q0 + w * 16 + quad * 4 + rr;
          if (key > qrow) s[nb][rr] = -1e30f;
        }
      }
    }
    // ---- online softmax (rows = quad*4+rr; reduce over 16-lane col group) ----
    float tm[4];
#pragma unroll
    for (int rr = 0; rr < 4; ++rr)
      tm[rr] = fmaxf(fmaxf(s[0][rr], s[1][rr]), fmaxf(s[2][rr], s[3][rr]));
#pragma unroll
    for (int off = 1; off < 16; off <<= 1)
#pragma unroll
      for (int rr = 0; rr < 4; ++rr)
        tm[rr] = fmaxf(tm[rr], __shfl_xor(tm[rr], off));
    float alpha[4], rs[4];
#pragma unroll
    for (int rr = 0; rr < 4; ++rr) {
      float mn = fmaxf(mrow[rr], tm[rr]);
      alpha[rr] = __expf(mrow[rr] - mn);
      mrow[rr] = mn;
      rs[rr] = 0.f;
    }
#pragma unroll
    for (int nb = 0; nb < 4; ++nb)
#pragma unroll
      for (int rr = 0; rr < 4; ++rr) {
        float ev = __expf(s[nb][rr] - mrow[rr]);
        rs[rr] += ev;
        ps[w][(quad * 4 + rr) * 72 + nb * 16 + col] = f2b(ev);
      }
#pragma unroll
    for (int off = 1; off < 16; off <<= 1)
#pragma unroll
      for (int rr = 0; rr < 4; ++rr)
        rs[rr] += __shfl_xor(rs[rr], off);
#pragma unroll
    for (int rr = 0; rr < 4; ++rr) lrow[rr] = lrow[rr] * alpha[rr] + rs[rr];
#pragma unroll
    for (int nb = 0; nb < 4; ++nb)
#pragma unroll
      for (int rr = 0; rr < 4; ++rr) acc[nb][rr] *= alpha[rr];

    // ---- PV: A = P (per-wave ps), B = V^T (vst, swizzled) ----
    bf16x8 pa0 = *(bf16x8*)&ps[w][col * 72 + quad * 8];
    bf16x8 pa1 = *(bf16x8*)&ps[w][col * 72 + 32 + quad * 8];
#pragma unroll
    for (int nb = 0; nb < 4; ++nb) {
      int d = nb * 16 + col;
      int sw = (d & 7) << 3;
      bf16x8 vb0 = *(bf16x8*)&vst[d * 64 + ((quad * 8) ^ sw)];
      bf16x8 vb1 = *(bf16x8*)&vst[d * 64 + ((32 + quad * 8) ^ sw)];
      acc[nb] = __builtin_amdgcn_mfma_f32_16x16x32_bf16(pa0, vb0, acc[nb], 0, 0, 0);
      acc[nb] = __builtin_amdgcn_mfma_f32_16x16x32_bf16(pa1, vb1, acc[nb], 0, 0, 0);
    }
  }
  // ---- epilogue ----
#pragma unroll
  for (int rr = 0; rr < 4; ++rr) {
    float inv = 1.f / lrow[rr];
    int qrow = q0 + w * 16 + quad * 4 + rr;
    size_t base = (size_t)(b * QS + qrow) * HID_ + h * 64;
#pragma unroll
    for (int nb = 0; nb < 4; ++nb)
      ctx[base + nb * 16 + col] = f2b(acc[nb][rr] * inv);
  }
}

// ---------------- host ----------------
extern "C" void kernel_launch(void* const* d_in, const int* in_sizes, int n_in,
                              void* d_out, int out_size, void* d_ws, size_t ws_size,
                              hipStream_t stream) {
  (void)in_sizes; (void)n_in; (void)out_size; (void)ws_size;
  const float* hs_f = (const float*)d_in[0];
  const float* kb_f = (const float*)d_in[1];
  const float* Wq   = (const float*)d_in[2];
  const float* Wk   = (const float*)d_in[3];
  const float* Wv   = (const float*)d_in[4];
  const float* Wo   = (const float*)d_in[5];
  const float* Wqn  = (const float*)d_in[6];
  const float* Wkbk = (const float*)d_in[7];
  const float* Wkbv = (const float*)d_in[8];
  const float* cosT = (const float*)d_in[9];
  const float* sinT = (const float*)d_in[10];
  const int*   pid  = (const int*)d_in[12];
  float* out = (float*)d_out;

  char* p = (char*)d_ws;
  u16* WT     = (u16*)p; p += (size_t)2048 * 2048 * 2;
  u16* hs_b   = (u16*)p; p += (size_t)B_ * QS * HID_ * 2;
  u16* kb_b   = (u16*)p; p += (size_t)B_ * KBN_ * HID_ * 2;
  u16* q_ws   = (u16*)p; p += (size_t)B_ * QS * HID_ * 2;
  u16* kbq_ws = (u16*)p; p += (size_t)B_ * QS * HID_ * 2;
  u16* k_ws   = (u16*)p; p += (size_t)B_ * QS * 512 * 2;
  u16* v_ws   = (u16*)p; p += (size_t)B_ * QS * 512 * 2;
  u16* kbk_ws = (u16*)p; p += (size_t)B_ * KBN_ * 512 * 2;
  u16* kbv_ws = (u16*)p; p += (size_t)B_ * KBN_ * 512 * 2;
  u16* ctx_ws = (u16*)p; p += (size_t)B_ * QS * HID_ * 2;
  double* hssum_ws = (double*)p; p += (size_t)B_ * HID_ * 8;
  double* S_ws     = (double*)p; p += (size_t)B_ * 512 * 8;
  double* U_ws     = (double*)p; p += (size_t)B_ * HID_ * 8;
  float*  sel_ws   = (float*)p;  p += (size_t)B_ * KBN_ * 4;
  int*    idx_ws   = (int*)p;    p += (size_t)B_ * TOPK_ * 4;

  dim3 blk(256);
  cast_f2b<<<dim3((B_ * QS * HID_ / 4 + 255) / 256), blk, 0, stream>>>(hs_f, hs_b, B_ * QS * HID_ / 4);
  cast_f2b<<<dim3((B_ * KBN_ * HID_ / 4 + 255) / 256), blk, 0, stream>>>(kb_f, kb_b, B_ * KBN_ * HID_ / 4);
  transpose_cast_k<<<dim3(64, 64), blk, 0, stream>>>(Wq, WT, 2048, 2048);
  gemm_nt<false><<<dim3(32, 16), blk, 0, stream>>>(hs_b, WT, q_ws, 2048, 2048, 2048);
  transpose_cast_k<<<dim3(64, 64), blk, 0, stream>>>(Wqn, WT, 2048, 2048);
  gemm_nt<false><<<dim3(32, 16), blk, 0, stream>>>(hs_b, WT, kbq_ws, 2048, 2048, 2048);
  transpose_cast_k<<<dim3(16, 64), blk, 0, stream>>>(Wk, WT, 2048, 512);
  gemm_nt<false><<<dim3(8, 16), blk, 0, stream>>>(hs_b, WT, k_ws, 2048, 512, 2048);
  transpose_cast_k<<<dim3(16, 64), blk, 0, stream>>>(Wv, WT, 2048, 512);
  gemm_nt<false><<<dim3(8, 16), blk, 0, stream>>>(hs_b, WT, v_ws, 2048, 512, 2048);
  transpose_cast_k<<<dim3(16, 64), blk, 0, stream>>>(Wkbk, WT, 2048, 512);
  gemm_nt<false><<<dim3(8, 8), blk, 0, stream>>>(kb_b, WT, kbk_ws, 1024, 512, 2048);
  transpose_cast_k<<<dim3(16, 64), blk, 0, stream>>>(Wkbv, WT, 2048, 512);
  gemm_nt<false><<<dim3(8, 8), blk, 0, stream>>>(kb_b, WT, kbv_ws, 1024, 512, 2048);
  rope_k<<<dim3((B_ * QS * NH_ * 32) / 256), blk, 0, stream>>>(q_ws, cosT, sinT, pid, NH_, B_ * QS * NH_ * 32);
  rope_k<<<dim3((B_ * QS * NKV_ * 32) / 256), blk, 0, stream>>>(k_ws, cosT, sinT, pid, NKV_, B_ * QS * NKV_ * 32);
  hssum_k<<<dim3(B_ * 8), blk, 0, stream>>>(hs_f, hssum_ws);
  selS_k<<<dim3(B_), dim3(512), 0, stream>>>(hssum_ws, Wqn, S_ws);
  selU_k<<<dim3(B_ * 8), blk, 0, stream>>>(S_ws, Wkbk, U_ws);
  self_k<<<dim3(B_ * 2), blk, 0, stream>>>(U_ws, kb_f, sel_ws);
  topk_k<<<dim3(B_), blk, 0, stream>>>(sel_ws, idx_ws);
  attn_mfma_k<<<dim3(QS / 64, NH_, B_), blk, 0, stream>>>(q_ws, k_ws, v_ws, kbq_ws, kbk_ws, kbv_ws, idx_ws, ctx_ws);
  transpose_cast_k<<<dim3(64, 64), blk, 0, stream>>>(Wo, WT, 2048, 2048);
  gemm_nt<true><<<dim3(32, 16), blk, 0, stream>>>(ctx_ws, WT, out, 2048, 2048, 2048);
}

// Round 5
// 726.905 us; speedup vs baseline: 1.9025x; 1.3644x over previous
//
#include <hip/hip_runtime.h>

typedef unsigned short u16;
typedef unsigned int   u32;
typedef __bf16 bf16_t;
typedef bf16_t bf16x8 __attribute__((ext_vector_type(8)));
typedef float  floatx4 __attribute__((ext_vector_type(4)));

#define B_    2
#define QS    1024
#define HID_  2048
#define NH_   32
#define NKV_  8
#define HD_   64
#define KBN_  512
#define TOPK_ 100

__device__ __forceinline__ float b2f(u16 u) {
  union { u32 i; float f; } x; x.i = ((u32)u) << 16; return x.f;
}
__device__ __forceinline__ u16 f2b(float f) {
  union { float f; u32 i; } x; x.f = f;
  u32 r = x.i + 0x7fffu + ((x.i >> 16) & 1u);
  return (u16)(r >> 16);
}

// ---------------- f32 -> bf16 cast (vectorized: 4 elems/thread) ----------------
__global__ __launch_bounds__(256)
void cast_f2b(const float* __restrict__ x, u16* __restrict__ y, int n4) {
  int i = blockIdx.x * 256 + threadIdx.x;
  if (i >= n4) return;
  float4 v = ((const float4*)x)[i];
  ((uint2*)y)[i] = make_uint2((u32)f2b(v.x) | ((u32)f2b(v.y) << 16),
                              (u32)f2b(v.z) | ((u32)f2b(v.w) << 16));
}

// ---------------- transpose+cast: WT[n*K+k] = bf16(W[k*N+n]), W is f32 ----------------
__global__ __launch_bounds__(256)
void transpose_cast_k(const float* __restrict__ W, u16* __restrict__ WT, int K, int N) {
  __shared__ float tile[32][33];
  int n0 = blockIdx.x * 32, k0 = blockIdx.y * 32;
  int tx = threadIdx.x & 31, ty = threadIdx.x >> 5;  // 32 x 8
#pragma unroll
  for (int i = 0; i < 32; i += 8)
    tile[ty + i][tx] = W[(size_t)(k0 + ty + i) * N + n0 + tx];
  __syncthreads();
#pragma unroll
  for (int i = 0; i < 32; i += 8)
    WT[(size_t)(n0 + ty + i) * K + k0 + tx] = f2b(tile[tx][ty + i]);
}

// ---------------- GEMM: C[M,N] = A[M,K] * B[K,N], BT is N x K (bf16 in) ----------------
template <bool OUTF32>
__global__ __launch_bounds__(256)
void gemm_nt(const u16* __restrict__ A, const u16* __restrict__ BT,
             void* __restrict__ Cv, int M, int N, int K) {
  __shared__ __align__(16) u16 asf[8 * 64 * 8];
  __shared__ __align__(16) u16 bsf[4 * 64 * 8];
  int t = threadIdx.x;
  int lane = t & 63, w = t >> 6;
  int m0 = blockIdx.y * 128, n0 = blockIdx.x * 64;
  int fr = lane & 15;
  int ko = (lane >> 4) * 8;
  const u16* Ap0 = A + (size_t)(m0 + w * 16 + fr) * K + ko;
  const u16* Ap1 = A + (size_t)(m0 + (w + 4) * 16 + fr) * K + ko;
  const u16* Bp  = BT + (size_t)(n0 + w * 16 + fr) * K + ko;
  u16* as0 = &asf[(w * 64 + lane) * 8];
  u16* as1 = &asf[((w + 4) * 64 + lane) * 8];
  u16* bs0 = &bsf[(w * 64 + lane) * 8];
  floatx4 acc0[4], acc1[4];
#pragma unroll
  for (int c = 0; c < 4; ++c) {
    acc0[c] = (floatx4){0.f, 0.f, 0.f, 0.f};
    acc1[c] = (floatx4){0.f, 0.f, 0.f, 0.f};
  }
  for (int k0 = 0; k0 < K; k0 += 32) {
    __syncthreads();
    *(uint4*)as0 = *(const uint4*)(Ap0 + k0);
    *(uint4*)as1 = *(const uint4*)(Ap1 + k0);
    *(uint4*)bs0 = *(const uint4*)(Bp + k0);
    __syncthreads();
    bf16x8 a0 = *(bf16x8*)&asf[((2 * w) * 64 + lane) * 8];
    bf16x8 a1 = *(bf16x8*)&asf[((2 * w + 1) * 64 + lane) * 8];
#pragma unroll
    for (int c = 0; c < 4; ++c) {
      bf16x8 bb = *(bf16x8*)&bsf[(c * 64 + lane) * 8];
      acc0[c] = __builtin_amdgcn_mfma_f32_16x16x32_bf16(a0, bb, acc0[c], 0, 0, 0);
      acc1[c] = __builtin_amdgcn_mfma_f32_16x16x32_bf16(a1, bb, acc1[c], 0, 0, 0);
    }
  }
  int orow = (lane >> 4) * 4, ocol = lane & 15;
#pragma unroll
  for (int c = 0; c < 4; ++c)
#pragma unroll
    for (int r = 0; r < 4; ++r) {
      size_t i0 = (size_t)(m0 + 32 * w + orow + r) * N + n0 + 16 * c + ocol;
      size_t i1 = (size_t)(m0 + 32 * w + 16 + orow + r) * N + n0 + 16 * c + ocol;
      if constexpr (OUTF32) {
        ((float*)Cv)[i0] = acc0[c][r];
        ((float*)Cv)[i1] = acc1[c][r];
      } else {
        ((u16*)Cv)[i0] = f2b(acc0[c][r]);
        ((u16*)Cv)[i1] = f2b(acc1[c][r]);
      }
    }
}

// ---------------- RoPE (in place on bf16), cos/sin are f32 [Q,64] ----------------
__global__ __launch_bounds__(256)
void rope_k(u16* __restrict__ x, const float* __restrict__ ct, const float* __restrict__ st,
            const int* __restrict__ pid, int nh, int total) {
  int gid = blockIdx.x * 256 + threadIdx.x;
  if (gid >= total) return;
  int per_row = nh * 32;
  int row = gid / per_row;
  int rem = gid - row * per_row;
  int h = rem >> 5, d = rem & 31;
  int pos = pid[row];
  float c = ct[pos * 64 + d];
  float s = st[pos * 64 + d];
  size_t base = (size_t)row * (nh * 64) + h * 64 + d;
  float x0 = b2f(x[base]), x1 = b2f(x[base + 32]);
  x[base]      = f2b(x0 * c - x1 * s);
  x[base + 32] = f2b(x1 * c + x0 * s);
}

// ======== high-precision selection path (f32 inputs, double accumulate) ========
// All stages two-stage partial+reduce, parallelized to machine width.

// generic chunk reduce: out[i] = sum_c part[c*len + i]
__global__ __launch_bounds__(256)
void red_d_k(const double* __restrict__ part, double* __restrict__ out, int nchunk, int len) {
  int i = blockIdx.x * 256 + threadIdx.x;
  if (i >= len) return;
  double a = 0.0;
  for (int c = 0; c < nchunk; ++c) a += part[(size_t)c * len + i];
  out[i] = a;
}
__global__ __launch_bounds__(256)
void red_f_k(const double* __restrict__ part, float* __restrict__ out, int nchunk, int len) {
  int i = blockIdx.x * 256 + threadIdx.x;
  if (i >= len) return;
  double a = 0.0;
  for (int c = 0; c < nchunk; ++c) a += part[(size_t)c * len + i];
  out[i] = (float)a;
}

// hssum partial: grid (64, B_), 256 thr. part[qc][b*HID_+c] = sum over 16 q-rows
__global__ __launch_bounds__(256)
void hssum_part_k(const float* __restrict__ hs, double* __restrict__ part) {
  int qc = blockIdx.x, b = blockIdx.y, t = threadIdx.x;
  double a[8] = {0, 0, 0, 0, 0, 0, 0, 0};
  for (int qq = 0; qq < 16; ++qq) {
    const float* row = hs + (size_t)(b * QS + qc * 16 + qq) * HID_;
#pragma unroll
    for (int m = 0; m < 8; ++m) a[m] += (double)row[m * 256 + t];
  }
#pragma unroll
  for (int m = 0; m < 8; ++m)
    part[(size_t)qc * (B_ * HID_) + b * HID_ + m * 256 + t] = a[m];
}

// selS partial: grid (128, B_), 512 thr.
// part[chunk][b*512+j] = sum_{c in chunk} hssum[b][c] * (w[0]+w[64]+w[128]+w[192])
__global__ __launch_bounds__(512)
void selS_part_k(const double* __restrict__ hssum, const float* __restrict__ Wqn,
                 double* __restrict__ part) {
  int chunk = blockIdx.x, b = blockIdx.y, j = threadIdx.x;
  int g = j >> 6, d = j & 63;
  int c0 = chunk * 16;
  double acc = 0.0;
  for (int cc = 0; cc < 16; ++cc) {
    int c = c0 + cc;
    const float* w = Wqn + (size_t)c * HID_ + g * 256 + d;
    acc += hssum[b * HID_ + c] *
           ((double)w[0] + (double)w[64] + (double)w[128] + (double)w[192]);
  }
  part[(size_t)chunk * (B_ * 512) + b * 512 + j] = acc;
}

// selU partial: grid (4, B_*8), 256 thr. part[jc][b*HID_+c] over 128 j
__global__ __launch_bounds__(256)
void selU_part_k(const double* __restrict__ S, const float* __restrict__ Wkbk,
                 double* __restrict__ part) {
  int jc = blockIdx.x;
  int b = blockIdx.y >> 3;
  int c = (blockIdx.y & 7) * 256 + threadIdx.x;
  const float* row = Wkbk + (size_t)c * 512 + jc * 128;
  const double* Sp = S + b * 512 + jc * 128;
  double acc = 0.0;
  for (int j = 0; j < 128; j += 4) {
    float4 wv = *(const float4*)(row + j);
    acc += Sp[j] * (double)wv.x + Sp[j + 1] * (double)wv.y +
           Sp[j + 2] * (double)wv.z + Sp[j + 3] * (double)wv.w;
  }
  part[(size_t)jc * (B_ * HID_) + b * HID_ + c] = acc;
}

// self partial: grid (2, 8, B_), 256 thr. part[cc][b*KBN_+n] over 256 c
__global__ __launch_bounds__(256)
void self_part_k(const double* __restrict__ U, const float* __restrict__ kbin,
                 double* __restrict__ part) {
  int n = blockIdx.x * 256 + threadIdx.x;
  int cc = blockIdx.y, b = blockIdx.z;
  const float* row = kbin + (size_t)(b * KBN_ + n) * HID_ + cc * 256;
  const double* u = U + b * HID_ + cc * 256;
  double acc = 0.0;
  for (int c = 0; c < 256; c += 4) {
    float4 kv = *(const float4*)(row + c);
    acc += u[c] * (double)kv.x + u[c + 1] * (double)kv.y +
           u[c + 2] * (double)kv.z + u[c + 3] * (double)kv.w;
  }
  part[(size_t)cc * (B_ * KBN_) + b * KBN_ + n] = acc;
}

// ---------------- top-100, single wave, register selection sort ----------------
__global__ __launch_bounds__(64)
void topk_k(const float* __restrict__ sel, int* __restrict__ idx) {
  int b = blockIdx.x, lane = threadIdx.x;
  int base = lane * 8;
  float v[8];
#pragma unroll
  for (int i = 0; i < 8; ++i) v[i] = sel[b * KBN_ + base + i];
  for (int it = 0; it < TOPK_; ++it) {
    float best = v[0]; int bi = 0;
#pragma unroll
    for (int i = 1; i < 8; ++i)
      if (v[i] > best) { best = v[i]; bi = i; }
    int gidx = base + bi;
#pragma unroll
    for (int off = 32; off >= 1; off >>= 1) {
      float ov = __shfl_xor(best, off);
      int og = __shfl_xor(gidx, off);
      if (ov > best || (ov == best && og < gidx)) { best = ov; gidx = og; }
    }
    if (lane == 0) idx[b * TOPK_ + it] = gidx;
    if ((gidx >> 3) == lane) v[gidx & 7] = -3e38f;
  }
}

// ---------------- MFMA flash attention ----------------
__global__ __launch_bounds__(256)
void attn_mfma_k(const u16* __restrict__ q, const u16* __restrict__ k, const u16* __restrict__ v,
                 const u16* __restrict__ kbq, const u16* __restrict__ kbk, const u16* __restrict__ kbv,
                 const int* __restrict__ topidx, u16* __restrict__ ctx) {
  int qt = blockIdx.x, h = blockIdx.y, b = blockIdx.z;
  int g = h >> 2;
  int t = threadIdx.x, lane = t & 63, w = t >> 6;
  int quad = lane >> 4, col = lane & 15;
  __shared__ __align__(16) u16 ks[64 * 72];      // [key][dim], pad 72 (144B stride)
  __shared__ __align__(16) u16 vst[64 * 64];     // [dim][key ^ ((dim&7)<<3)] swizzled
  __shared__ __align__(16) u16 ps[4][16 * 72];   // per-wave P tile [row][key]
  const float LOGADJ = 1.6331544f;               // ln(512/100)
  int q0 = qt * 64;

  int qrow_frag = q0 + w * 16 + col;
  bf16x8 aKB[2], aC[2];
#pragma unroll
  for (int kstep = 0; kstep < 2; ++kstep) {
    const u16* p1 = kbq + (size_t)(b * QS + qrow_frag) * HID_ + h * 64 + kstep * 32 + quad * 8;
    const u16* p2 = q   + (size_t)(b * QS + qrow_frag) * HID_ + h * 64 + kstep * 32 + quad * 8;
    uint4 x1 = *(const uint4*)p1, x2 = *(const uint4*)p2;
    const u16* u1 = (const u16*)&x1; const u16* u2 = (const u16*)&x2;
#pragma unroll
    for (int i = 0; i < 8; ++i) {
      aKB[kstep][i] = (bf16_t)(0.125f * b2f(u1[i]));
      aC[kstep][i]  = (bf16_t)(0.125f * b2f(u2[i]));
    }
  }

  float mrow[4] = {-1e30f, -1e30f, -1e30f, -1e30f};
  float lrow[4] = {0.f, 0.f, 0.f, 0.f};
  floatx4 acc[4];
#pragma unroll
  for (int nb = 0; nb < 4; ++nb) acc[nb] = (floatx4){0.f, 0.f, 0.f, 0.f};

  int ntiles = 2 + (q0 >> 6) + 1;
  for (int tile = 0; tile < ntiles; ++tile) {
    __syncthreads();
    {  // stage ks
      int j = t >> 2, dc = (t & 3) * 16;
      const u16* src;
      if (tile < 2) {
        int slot = tile * 64 + j;
        int n = topidx[b * TOPK_ + (slot < TOPK_ ? slot : TOPK_ - 1)];
        src = kbk + (size_t)(b * KBN_ + n) * 512 + g * 64 + dc;
      } else {
        int key = (tile - 2) * 64 + j;
        src = k + (size_t)(b * QS + key) * 512 + g * 64 + dc;
      }
      *(uint4*)&ks[j * 72 + dc]     = *(const uint4*)src;
      *(uint4*)&ks[j * 72 + dc + 8] = *(const uint4*)(src + 8);
    }
    {  // stage vst transposed+swizzled
      int d = t & 63, kc = t >> 6;
      __align__(16) u16 tmp[16];
      if (tile < 2) {
#pragma unroll
        for (int i = 0; i < 16; ++i) {
          int slot = tile * 64 + kc * 16 + i;
          int n = topidx[b * TOPK_ + (slot < TOPK_ ? slot : TOPK_ - 1)];
          tmp[i] = kbv[(size_t)(b * KBN_ + n) * 512 + g * 64 + d];
        }
      } else {
        const u16* src = v + (size_t)(b * QS + (tile - 2) * 64 + kc * 16) * 512 + g * 64 + d;
#pragma unroll
        for (int i = 0; i < 16; ++i) tmp[i] = src[(size_t)i * 512];
      }
      int sw = d & 7;
      *(uint4*)&vst[d * 64 + ((2 * kc) ^ sw) * 8]     = *(uint4*)&tmp[0];
      *(uint4*)&vst[d * 64 + ((2 * kc + 1) ^ sw) * 8] = *(uint4*)&tmp[8];
    }
    __syncthreads();

    bf16x8 aq0 = (tile < 2) ? aKB[0] : aC[0];
    bf16x8 aq1 = (tile < 2) ? aKB[1] : aC[1];
    floatx4 s[4];
#pragma unroll
    for (int nb = 0; nb < 4; ++nb) {
      s[nb] = (floatx4){0.f, 0.f, 0.f, 0.f};
      bf16x8 b0 = *(bf16x8*)&ks[(nb * 16 + col) * 72 + quad * 8];
      bf16x8 b1 = *(bf16x8*)&ks[(nb * 16 + col) * 72 + 32 + quad * 8];
      s[nb] = __builtin_amdgcn_mfma_f32_16x16x32_bf16(aq0, b0, s[nb], 0, 0, 0);
      s[nb] = __builtin_amdgcn_mfma_f32_16x16x32_bf16(aq1, b1, s[nb], 0, 0, 0);
    }
    if (tile < 2) {
#pragma unroll
      for (int nb = 0; nb < 4; ++nb) {
        int slot = tile * 64 + nb * 16 + col;
        bool dead = (slot >= TOPK_);
#pragma unroll
        for (int rr = 0; rr < 4; ++rr)
          s[nb][rr] = dead ? -1e30f : (s[nb][rr] + LOGADJ);
      }
    } else {
      int kbase = (tile - 2) * 64;
#pragma unroll
      for (int nb = 0; nb < 4; ++nb) {
        int key = kbase + nb * 16 + col;
#pragma unroll
        for (int rr = 0; rr < 4; ++rr) {
          int qrow = q0 + w * 16 + quad * 4 + rr;
          if (key > qrow) s[nb][rr] = -1e30f;
        }
      }
    }
    float tm[4];
#pragma unroll
    for (int rr = 0; rr < 4; ++rr)
      tm[rr] = fmaxf(fmaxf(s[0][rr], s[1][rr]), fmaxf(s[2][rr], s[3][rr]));
#pragma unroll
    for (int off = 1; off < 16; off <<= 1)
#pragma unroll
      for (int rr = 0; rr < 4; ++rr)
        tm[rr] = fmaxf(tm[rr], __shfl_xor(tm[rr], off));
    float alpha[4], rs[4];
#pragma unroll
    for (int rr = 0; rr < 4; ++rr) {
      float mn = fmaxf(mrow[rr], tm[rr]);
      alpha[rr] = __expf(mrow[rr] - mn);
      mrow[rr] = mn;
      rs[rr] = 0.f;
    }
#pragma unroll
    for (int nb = 0; nb < 4; ++nb)
#pragma unroll
      for (int rr = 0; rr < 4; ++rr) {
        float ev = __expf(s[nb][rr] - mrow[rr]);
        rs[rr] += ev;
        ps[w][(quad * 4 + rr) * 72 + nb * 16 + col] = f2b(ev);
      }
#pragma unroll
    for (int off = 1; off < 16; off <<= 1)
#pragma unroll
      for (int rr = 0; rr < 4; ++rr)
        rs[rr] += __shfl_xor(rs[rr], off);
#pragma unroll
    for (int rr = 0; rr < 4; ++rr) lrow[rr] = lrow[rr] * alpha[rr] + rs[rr];
#pragma unroll
    for (int nb = 0; nb < 4; ++nb)
#pragma unroll
      for (int rr = 0; rr < 4; ++rr) acc[nb][rr] *= alpha[rr];

    bf16x8 pa0 = *(bf16x8*)&ps[w][col * 72 + quad * 8];
    bf16x8 pa1 = *(bf16x8*)&ps[w][col * 72 + 32 + quad * 8];
#pragma unroll
    for (int nb = 0; nb < 4; ++nb) {
      int d = nb * 16 + col;
      int sw = (d & 7) << 3;
      bf16x8 vb0 = *(bf16x8*)&vst[d * 64 + ((quad * 8) ^ sw)];
      bf16x8 vb1 = *(bf16x8*)&vst[d * 64 + ((32 + quad * 8) ^ sw)];
      acc[nb] = __builtin_amdgcn_mfma_f32_16x16x32_bf16(pa0, vb0, acc[nb], 0, 0, 0);
      acc[nb] = __builtin_amdgcn_mfma_f32_16x16x32_bf16(pa1, vb1, acc[nb], 0, 0, 0);
    }
  }
#pragma unroll
  for (int rr = 0; rr < 4; ++rr) {
    float inv = 1.f / lrow[rr];
    int qrow = q0 + w * 16 + quad * 4 + rr;
    size_t base = (size_t)(b * QS + qrow) * HID_ + h * 64;
#pragma unroll
    for (int nb = 0; nb < 4; ++nb)
      ctx[base + nb * 16 + col] = f2b(acc[nb][rr] * inv);
  }
}

// ---------------- host ----------------
extern "C" void kernel_launch(void* const* d_in, const int* in_sizes, int n_in,
                              void* d_out, int out_size, void* d_ws, size_t ws_size,
                              hipStream_t stream) {
  (void)in_sizes; (void)n_in; (void)out_size; (void)ws_size;
  const float* hs_f = (const float*)d_in[0];
  const float* kb_f = (const float*)d_in[1];
  const float* Wq   = (const float*)d_in[2];
  const float* Wk   = (const float*)d_in[3];
  const float* Wv   = (const float*)d_in[4];
  const float* Wo   = (const float*)d_in[5];
  const float* Wqn  = (const float*)d_in[6];
  const float* Wkbk = (const float*)d_in[7];
  const float* Wkbv = (const float*)d_in[8];
  const float* cosT = (const float*)d_in[9];
  const float* sinT = (const float*)d_in[10];
  const int*   pid  = (const int*)d_in[12];
  float* out = (float*)d_out;

  char* p = (char*)d_ws;
  u16* WT     = (u16*)p; p += (size_t)2048 * 2048 * 2;
  u16* hs_b   = (u16*)p; p += (size_t)B_ * QS * HID_ * 2;
  u16* kb_b   = (u16*)p; p += (size_t)B_ * KBN_ * HID_ * 2;
  u16* q_ws   = (u16*)p; p += (size_t)B_ * QS * HID_ * 2;
  u16* kbq_ws = (u16*)p; p += (size_t)B_ * QS * HID_ * 2;
  u16* k_ws   = (u16*)p; p += (size_t)B_ * QS * 512 * 2;
  u16* v_ws   = (u16*)p; p += (size_t)B_ * QS * 512 * 2;
  u16* kbk_ws = (u16*)p; p += (size_t)B_ * KBN_ * 512 * 2;
  u16* kbv_ws = (u16*)p; p += (size_t)B_ * KBN_ * 512 * 2;
  u16* ctx_ws = (u16*)p; p += (size_t)B_ * QS * HID_ * 2;
  double* hssum_ws = (double*)p; p += (size_t)B_ * HID_ * 8;
  double* S_ws     = (double*)p; p += (size_t)B_ * 512 * 8;
  double* U_ws     = (double*)p; p += (size_t)B_ * HID_ * 8;
  float*  sel_ws   = (float*)p;  p += (size_t)B_ * KBN_ * 4;
  int*    idx_ws   = (int*)p;    p += (size_t)B_ * TOPK_ * 4;
  double* partH    = (double*)p; p += (size_t)64 * B_ * HID_ * 8;   // 2 MB
  double* partS    = (double*)p; p += (size_t)128 * B_ * 512 * 8;   // 1 MB
  double* partU    = (double*)p; p += (size_t)4 * B_ * HID_ * 8;    // 128 KB
  double* partSel  = (double*)p; p += (size_t)8 * B_ * KBN_ * 8;    // 64 KB

  dim3 blk(256);
  cast_f2b<<<dim3((B_ * QS * HID_ / 4 + 255) / 256), blk, 0, stream>>>(hs_f, hs_b, B_ * QS * HID_ / 4);
  cast_f2b<<<dim3((B_ * KBN_ * HID_ / 4 + 255) / 256), blk, 0, stream>>>(kb_f, kb_b, B_ * KBN_ * HID_ / 4);
  transpose_cast_k<<<dim3(64, 64), blk, 0, stream>>>(Wq, WT, 2048, 2048);
  gemm_nt<false><<<dim3(32, 16), blk, 0, stream>>>(hs_b, WT, q_ws, 2048, 2048, 2048);
  transpose_cast_k<<<dim3(64, 64), blk, 0, stream>>>(Wqn, WT, 2048, 2048);
  gemm_nt<false><<<dim3(32, 16), blk, 0, stream>>>(hs_b, WT, kbq_ws, 2048, 2048, 2048);
  transpose_cast_k<<<dim3(16, 64), blk, 0, stream>>>(Wk, WT, 2048, 512);
  gemm_nt<false><<<dim3(8, 16), blk, 0, stream>>>(hs_b, WT, k_ws, 2048, 512, 2048);
  transpose_cast_k<<<dim3(16, 64), blk, 0, stream>>>(Wv, WT, 2048, 512);
  gemm_nt<false><<<dim3(8, 16), blk, 0, stream>>>(hs_b, WT, v_ws, 2048, 512, 2048);
  transpose_cast_k<<<dim3(16, 64), blk, 0, stream>>>(Wkbk, WT, 2048, 512);
  gemm_nt<false><<<dim3(8, 8), blk, 0, stream>>>(kb_b, WT, kbk_ws, 1024, 512, 2048);
  transpose_cast_k<<<dim3(16, 64), blk, 0, stream>>>(Wkbv, WT, 2048, 512);
  gemm_nt<false><<<dim3(8, 8), blk, 0, stream>>>(kb_b, WT, kbv_ws, 1024, 512, 2048);
  rope_k<<<dim3((B_ * QS * NH_ * 32) / 256), blk, 0, stream>>>(q_ws, cosT, sinT, pid, NH_, B_ * QS * NH_ * 32);
  rope_k<<<dim3((B_ * QS * NKV_ * 32) / 256), blk, 0, stream>>>(k_ws, cosT, sinT, pid, NKV_, B_ * QS * NKV_ * 32);
  // selection path (parallelized, deterministic two-stage)
  hssum_part_k<<<dim3(64, B_), blk, 0, stream>>>(hs_f, partH);
  red_d_k<<<dim3((B_ * HID_ + 255) / 256), blk, 0, stream>>>(partH, hssum_ws, 64, B_ * HID_);
  selS_part_k<<<dim3(128, B_), dim3(512), 0, stream>>>(hssum_ws, Wqn, partS);
  red_d_k<<<dim3((B_ * 512 + 255) / 256), blk, 0, stream>>>(partS, S_ws, 128, B_ * 512);
  selU_part_k<<<dim3(4, B_ * 8), blk, 0, stream>>>(S_ws, Wkbk, partU);
  red_d_k<<<dim3((B_ * HID_ + 255) / 256), blk, 0, stream>>>(partU, U_ws, 4, B_ * HID_);
  self_part_k<<<dim3(2, 8, B_), blk, 0, stream>>>(U_ws, kb_f, partSel);
  red_f_k<<<dim3((B_ * KBN_ + 255) / 256), blk, 0, stream>>>(partSel, sel_ws, 8, B_ * KBN_);
  topk_k<<<dim3(B_), dim3(64), 0, stream>>>(sel_ws, idx_ws);
  // attention + output projection
  attn_mfma_k<<<dim3(QS / 64, NH_, B_), blk, 0, stream>>>(q_ws, k_ws, v_ws, kbq_ws, kbk_ws, kbv_ws, idx_ws, ctx_ws);
  transpose_cast_k<<<dim3(64, 64), blk, 0, stream>>>(Wo, WT, 2048, 2048);
  gemm_nt<true><<<dim3(32, 16), blk, 0, stream>>>(ctx_ws, WT, out, 2048, 2048, 2048);
}

// Round 7
// 621.298 us; speedup vs baseline: 2.2259x; 1.1700x over previous
//
#include <hip/hip_runtime.h>

typedef unsigned short u16;
typedef unsigned int   u32;
typedef __bf16 bf16_t;
typedef bf16_t bf16x8 __attribute__((ext_vector_type(8)));
typedef float  floatx4 __attribute__((ext_vector_type(4)));

#define B_    2
#define QS    1024
#define HID_  2048
#define NH_   32
#define NKV_  8
#define HD_   64
#define KBN_  512
#define TOPK_ 100
#define FS    5120   // fused projection row stride: q|k|v|kbq = 0|2048|2560|3072

__device__ __forceinline__ float b2f(u16 u) {
  union { u32 i; float f; } x; x.i = ((u32)u) << 16; return x.f;
}
__device__ __forceinline__ u16 f2b(float f) {
  union { float f; u32 i; } x; x.f = f;
  u32 r = x.i + 0x7fffu + ((x.i >> 16) & 1u);
  return (u16)(r >> 16);
}
__device__ __forceinline__ void async16(const u16* g, u16* l) {
  __builtin_amdgcn_global_load_lds(
      (const __attribute__((address_space(1))) unsigned int*)g,
      (__attribute__((address_space(3))) unsigned int*)l, 16, 0, 0);
}

// ---------------- f32 -> bf16 cast ----------------
__global__ __launch_bounds__(256)
void cast_f2b(const float* __restrict__ x, u16* __restrict__ y, int n4) {
  int i = blockIdx.x * 256 + threadIdx.x;
  if (i >= n4) return;
  float4 v = ((const float4*)x)[i];
  ((uint2*)y)[i] = make_uint2((u32)f2b(v.x) | ((u32)f2b(v.y) << 16),
                              (u32)f2b(v.z) | ((u32)f2b(v.w) << 16));
}

// ---------------- transpose+cast: WT[n*K+k] = bf16(W[k*N+n]) ----------------
__global__ __launch_bounds__(256)
void transpose_cast_k(const float* __restrict__ W, u16* __restrict__ WT, int K, int N) {
  __shared__ float tile[32][33];
  int n0 = blockIdx.x * 32, k0 = blockIdx.y * 32;
  int tx = threadIdx.x & 31, ty = threadIdx.x >> 5;
#pragma unroll
  for (int i = 0; i < 32; i += 8)
    tile[ty + i][tx] = W[(size_t)(k0 + ty + i) * N + n0 + tx];
  __syncthreads();
#pragma unroll
  for (int i = 0; i < 32; i += 8)
    WT[(size_t)(n0 + ty + i) * K + k0 + tx] = f2b(tile[tx][ty + i]);
}

// ---------------- GEMM m97-style: 128x128 tile, global_load_lds ----------------
// C[M,N] = A[M,K] * B[K,N], BT is N x K. CS = C row stride.
template <bool OUTF32>
__global__ __launch_bounds__(256)
void gemm_nt2(const u16* __restrict__ A, const u16* __restrict__ BT,
              void* __restrict__ Cv, int M, int N, int K, int CS) {
  __shared__ __align__(16) u16 asf[8 * 64 * 8];  // 8 m-blocks, fragment order
  __shared__ __align__(16) u16 bsf[8 * 64 * 8];  // 8 n-blocks, fragment order
  int t = threadIdx.x, lane = t & 63, w = t >> 6;
  int m0 = blockIdx.y * 128, n0 = blockIdx.x * 128;
  int fr = lane & 15, ko = (lane >> 4) * 8;
  const u16* Ap0 = A + (size_t)(m0 + w * 16 + fr) * K + ko;
  const u16* Ap1 = A + (size_t)(m0 + (w + 4) * 16 + fr) * K + ko;
  const u16* Bp0 = BT + (size_t)(n0 + w * 16 + fr) * K + ko;
  const u16* Bp1 = BT + (size_t)(n0 + (w + 4) * 16 + fr) * K + ko;
  u16* la0 = &asf[(w * 64) * 8];
  u16* la1 = &asf[((w + 4) * 64) * 8];
  u16* lb0 = &bsf[(w * 64) * 8];
  u16* lb1 = &bsf[((w + 4) * 64) * 8];
  int mh = (w >> 1) * 4, nh2 = (w & 1) * 4;
  floatx4 acc[4][4];
#pragma unroll
  for (int i = 0; i < 4; ++i)
#pragma unroll
    for (int j = 0; j < 4; ++j) acc[i][j] = (floatx4){0.f, 0.f, 0.f, 0.f};
  for (int k0 = 0; k0 < K; k0 += 32) {
    __syncthreads();
    async16(Ap0 + k0, la0);
    async16(Ap1 + k0, la1);
    async16(Bp0 + k0, lb0);
    async16(Bp1 + k0, lb1);
    __syncthreads();
    bf16x8 a[4], b[4];
#pragma unroll
    for (int mb = 0; mb < 4; ++mb) a[mb] = *(bf16x8*)&asf[((mh + mb) * 64 + lane) * 8];
#pragma unroll
    for (int nb = 0; nb < 4; ++nb) b[nb] = *(bf16x8*)&bsf[((nh2 + nb) * 64 + lane) * 8];
#pragma unroll
    for (int mb = 0; mb < 4; ++mb)
#pragma unroll
      for (int nb = 0; nb < 4; ++nb)
        acc[mb][nb] = __builtin_amdgcn_mfma_f32_16x16x32_bf16(a[mb], b[nb], acc[mb][nb], 0, 0, 0);
  }
  int quad = lane >> 4, col = lane & 15;
#pragma unroll
  for (int mb = 0; mb < 4; ++mb)
#pragma unroll
    for (int nb = 0; nb < 4; ++nb)
#pragma unroll
      for (int r = 0; r < 4; ++r) {
        size_t idx = (size_t)(m0 + (mh + mb) * 16 + quad * 4 + r) * CS +
                     n0 + (nh2 + nb) * 16 + col;
        if constexpr (OUTF32) ((float*)Cv)[idx] = acc[mb][nb][r];
        else                  ((u16*)Cv)[idx] = f2b(acc[mb][nb][r]);
      }
}

// ---------------- RoPE (in place on bf16, strided), cos/sin f32 [Q,64] ----------------
__global__ __launch_bounds__(256)
void rope_k(u16* __restrict__ x, int rs, const float* __restrict__ ct,
            const float* __restrict__ st, const int* __restrict__ pid, int nh, int total) {
  int gid = blockIdx.x * 256 + threadIdx.x;
  if (gid >= total) return;
  int per_row = nh * 32;
  int row = gid / per_row;
  int rem = gid - row * per_row;
  int h = rem >> 5, d = rem & 31;
  int pos = pid[row];
  float c = ct[pos * 64 + d];
  float s = st[pos * 64 + d];
  size_t base = (size_t)row * rs + h * 64 + d;
  float x0 = b2f(x[base]), x1 = b2f(x[base + 32]);
  x[base]      = f2b(x0 * c - x1 * s);
  x[base + 32] = f2b(x1 * c + x0 * s);
}

// ======== high-precision selection path (f32 inputs, double accumulate) ========
__global__ __launch_bounds__(256)
void red_d_k(const double* __restrict__ part, double* __restrict__ out, int nchunk, int len) {
  int i = blockIdx.x * 256 + threadIdx.x;
  if (i >= len) return;
  double a = 0.0;
  for (int c = 0; c < nchunk; ++c) a += part[(size_t)c * len + i];
  out[i] = a;
}
__global__ __launch_bounds__(256)
void red_f_k(const double* __restrict__ part, float* __restrict__ out, int nchunk, int len) {
  int i = blockIdx.x * 256 + threadIdx.x;
  if (i >= len) return;
  double a = 0.0;
  for (int c = 0; c < nchunk; ++c) a += part[(size_t)c * len + i];
  out[i] = (float)a;
}

__global__ __launch_bounds__(256)
void hssum_part_k(const float* __restrict__ hs, double* __restrict__ part) {
  int qc = blockIdx.x, b = blockIdx.y, t = threadIdx.x;
  double a[8] = {0, 0, 0, 0, 0, 0, 0, 0};
  for (int qq = 0; qq < 16; ++qq) {
    const float* row = hs + (size_t)(b * QS + qc * 16 + qq) * HID_;
#pragma unroll
    for (int m = 0; m < 8; ++m) a[m] += (double)row[m * 256 + t];
  }
#pragma unroll
  for (int m = 0; m < 8; ++m)
    part[(size_t)qc * (B_ * HID_) + b * HID_ + m * 256 + t] = a[m];
}

__global__ __launch_bounds__(512)
void selS_part_k(const double* __restrict__ hssum, const float* __restrict__ Wqn,
                 double* __restrict__ part) {
  int chunk = blockIdx.x, b = blockIdx.y, j = threadIdx.x;
  int g = j >> 6, d = j & 63;
  int c0 = chunk * 16;
  double acc = 0.0;
  for (int cc = 0; cc < 16; ++cc) {
    int c = c0 + cc;
    const float* w = Wqn + (size_t)c * HID_ + g * 256 + d;
    acc += hssum[b * HID_ + c] *
           ((double)w[0] + (double)w[64] + (double)w[128] + (double)w[192]);
  }
  part[(size_t)chunk * (B_ * 512) + b * 512 + j] = acc;
}

__global__ __launch_bounds__(256)
void selU_part_k(const double* __restrict__ S, const float* __restrict__ Wkbk,
                 double* __restrict__ part) {
  int jc = blockIdx.x;
  int b = blockIdx.y >> 3;
  int c = (blockIdx.y & 7) * 256 + threadIdx.x;
  const float* row = Wkbk + (size_t)c * 512 + jc * 128;
  const double* Sp = S + b * 512 + jc * 128;
  double acc = 0.0;
  for (int j = 0; j < 128; j += 4) {
    float4 wv = *(const float4*)(row + j);
    acc += Sp[j] * (double)wv.x + Sp[j + 1] * (double)wv.y +
           Sp[j + 2] * (double)wv.z + Sp[j + 3] * (double)wv.w;
  }
  part[(size_t)jc * (B_ * HID_) + b * HID_ + c] = acc;
}

__global__ __launch_bounds__(256)
void self_part_k(const double* __restrict__ U, const float* __restrict__ kbin,
                 double* __restrict__ part) {
  int n = blockIdx.x * 256 + threadIdx.x;
  int cc = blockIdx.y, b = blockIdx.z;
  const float* row = kbin + (size_t)(b * KBN_ + n) * HID_ + cc * 256;
  const double* u = U + b * HID_ + cc * 256;
  double acc = 0.0;
  for (int c = 0; c < 256; c += 4) {
    float4 kv = *(const float4*)(row + c);
    acc += u[c] * (double)kv.x + u[c + 1] * (double)kv.y +
           u[c + 2] * (double)kv.z + u[c + 3] * (double)kv.w;
  }
  part[(size_t)cc * (B_ * KBN_) + b * KBN_ + n] = acc;
}

// ---------------- top-100, single wave, register selection sort ----------------
__global__ __launch_bounds__(64)
void topk_k(const float* __restrict__ sel, int* __restrict__ idx) {
  int b = blockIdx.x, lane = threadIdx.x;
  int base = lane * 8;
  float v[8];
#pragma unroll
  for (int i = 0; i < 8; ++i) v[i] = sel[b * KBN_ + base + i];
  for (int it = 0; it < TOPK_; ++it) {
    float best = v[0]; int bi = 0;
#pragma unroll
    for (int i = 1; i < 8; ++i)
      if (v[i] > best) { best = v[i]; bi = i; }
    int gidx = base + bi;
#pragma unroll
    for (int off = 32; off >= 1; off >>= 1) {
      float ov = __shfl_xor(best, off);
      int og = __shfl_xor(gidx, off);
      if (ov > best || (ov == best && og < gidx)) { best = ov; gidx = og; }
    }
    if (lane == 0) idx[b * TOPK_ + it] = gidx;
    if ((gidx >> 3) == lane) v[gidx & 7] = -3e38f;
  }
}

// ---------------- V transpose: vt[(b*8+g)*64+d][key] = v[key][g*64+d] ----------------
__global__ __launch_bounds__(256)
void vtrans_k(const u16* __restrict__ fused, u16* __restrict__ vt) {
  int kt = blockIdx.x;           // key tile 0..15
  int bg = blockIdx.y;           // b*8+g
  int b = bg >> 3, g = bg & 7;
  int t = threadIdx.x;
  __shared__ u16 tile[64][72];
  {
    int kk = t >> 2, dc = (t & 3) * 16;
    const u16* src = fused + (size_t)(b * QS + kt * 64 + kk) * FS + 2560 + g * 64 + dc;
    *(uint4*)&tile[kk][dc]     = *(const uint4*)src;
    *(uint4*)&tile[kk][dc + 8] = *(const uint4*)(src + 8);
  }
  __syncthreads();
  {
    int d = t >> 2, kc = t & 3;
    __align__(16) u16 tmp[16];
#pragma unroll
    for (int i = 0; i < 16; ++i) tmp[i] = tile[kc * 16 + i][d];
    u16* dst = vt + ((size_t)bg * 64 + d) * 1024 + kt * 64 + kc * 16;
    *(uint4*)dst       = *(uint4*)&tmp[0];
    *(uint4*)(dst + 8) = *(uint4*)&tmp[8];
  }
}

// ---------------- top-k V gather: kbt[(b*8+g)*64+d][slot] ----------------
__global__ __launch_bounds__(256)
void kbgather_k(const u16* __restrict__ kbf, const int* __restrict__ topidx,
                u16* __restrict__ kbt) {
  int bg = blockIdx.x; int b = bg >> 3, g = bg & 7;
  int t = threadIdx.x;
  int d = t >> 2, s0 = (t & 3) * 32;
  __align__(16) u16 tmp[32];
#pragma unroll
  for (int i = 0; i < 32; ++i) {
    int slot = s0 + i;
    int n = topidx[b * TOPK_ + (slot < TOPK_ ? slot : TOPK_ - 1)];
    tmp[i] = kbf[(size_t)(b * KBN_ + n) * 1024 + 512 + g * 64 + d];
  }
  u16* dst = kbt + ((size_t)bg * 64 + d) * 128 + s0;
#pragma unroll
  for (int i = 0; i < 32; i += 8) *(uint4*)(dst + i) = *(uint4*)&tmp[i];
}

// ---------------- MFMA flash attention (fused-layout inputs) ----------------
__global__ __launch_bounds__(256)
void attn_mfma_k(const u16* __restrict__ fused, const u16* __restrict__ kbf,
                 const u16* __restrict__ vt, const u16* __restrict__ kbt,
                 const int* __restrict__ topidx, u16* __restrict__ ctx) {
  int qt = blockIdx.x, h = blockIdx.y, b = blockIdx.z;
  int g = h >> 2;
  int t = threadIdx.x, lane = t & 63, w = t >> 6;
  int quad = lane >> 4, col = lane & 15;
  __shared__ __align__(16) u16 ks[64 * 72];
  __shared__ __align__(16) u16 vst[64 * 64];
  __shared__ __align__(16) u16 ps[4][16 * 72];
  const float LOGADJ = 1.6331544f;  // ln(512/100)
  int q0 = qt * 64;

  int qrow_frag = q0 + w * 16 + col;
  bf16x8 aKB[2], aC[2];
#pragma unroll
  for (int kstep = 0; kstep < 2; ++kstep) {
    const u16* p1 = fused + (size_t)(b * QS + qrow_frag) * FS + 3072 + h * 64 + kstep * 32 + quad * 8;
    const u16* p2 = fused + (size_t)(b * QS + qrow_frag) * FS + 0    + h * 64 + kstep * 32 + quad * 8;
    uint4 x1 = *(const uint4*)p1, x2 = *(const uint4*)p2;
    const u16* u1 = (const u16*)&x1; const u16* u2 = (const u16*)&x2;
#pragma unroll
    for (int i = 0; i < 8; ++i) {
      aKB[kstep][i] = (bf16_t)(0.125f * b2f(u1[i]));
      aC[kstep][i]  = (bf16_t)(0.125f * b2f(u2[i]));
    }
  }

  float mrow[4] = {-1e30f, -1e30f, -1e30f, -1e30f};
  float lrow[4] = {0.f, 0.f, 0.f, 0.f};
  floatx4 acc[4];
#pragma unroll
  for (int nb = 0; nb < 4; ++nb) acc[nb] = (floatx4){0.f, 0.f, 0.f, 0.f};

  int ntiles = 2 + (q0 >> 6) + 1;
  for (int tile = 0; tile < ntiles; ++tile) {
    __syncthreads();
    {  // stage ks (row-major K tile)
      int j = t >> 2, dc = (t & 3) * 16;
      const u16* src;
      if (tile < 2) {
        int slot = tile * 64 + j;
        int n = topidx[b * TOPK_ + (slot < TOPK_ ? slot : TOPK_ - 1)];
        src = kbf + (size_t)(b * KBN_ + n) * 1024 + g * 64 + dc;
      } else {
        int key = (tile - 2) * 64 + j;
        src = fused + (size_t)(b * QS + key) * FS + 2048 + g * 64 + dc;
      }
      *(uint4*)&ks[j * 72 + dc]     = *(const uint4*)src;
      *(uint4*)&ks[j * 72 + dc + 8] = *(const uint4*)(src + 8);
    }
    {  // stage vst from pre-transposed V (coalesced), swizzled write
      int d = t >> 2, c4 = t & 3;
      const u16* src;
      if (tile < 2) src = kbt + ((size_t)(b * 8 + g) * 64 + d) * 128 + tile * 64 + c4 * 16;
      else          src = vt  + ((size_t)(b * 8 + g) * 64 + d) * 1024 + (tile - 2) * 64 + c4 * 16;
      uint4 lo = *(const uint4*)src, hi = *(const uint4*)(src + 8);
      int sw = d & 7;
      *(uint4*)&vst[d * 64 + ((2 * c4)     ^ sw) * 8] = lo;
      *(uint4*)&vst[d * 64 + ((2 * c4 + 1) ^ sw) * 8] = hi;
    }
    __syncthreads();

    bf16x8 aq0 = (tile < 2) ? aKB[0] : aC[0];
    bf16x8 aq1 = (tile < 2) ? aKB[1] : aC[1];
    floatx4 s[4];
#pragma unroll
    for (int nb = 0; nb < 4; ++nb) {
      s[nb] = (floatx4){0.f, 0.f, 0.f, 0.f};
      bf16x8 b0 = *(bf16x8*)&ks[(nb * 16 + col) * 72 + quad * 8];
      bf16x8 b1 = *(bf16x8*)&ks[(nb * 16 + col) * 72 + 32 + quad * 8];
      s[nb] = __builtin_amdgcn_mfma_f32_16x16x32_bf16(aq0, b0, s[nb], 0, 0, 0);
      s[nb] = __builtin_amdgcn_mfma_f32_16x16x32_bf16(aq1, b1, s[nb], 0, 0, 0);
    }
    if (tile < 2) {
#pragma unroll
      for (int nb = 0; nb < 4; ++nb) {
        int slot = tile * 64 + nb * 16 + col;
        bool dead = (slot >= TOPK_);
#pragma unroll
        for (int rr = 0; rr < 4; ++rr)
          s[nb][rr] = dead ? -1e30f : (s[nb][rr] + LOGADJ);
      }
    } else {
      int kbase = (tile - 2) * 64;
#pragma unroll
      for (int nb = 0; nb < 4; ++nb) {
        int key = kbase + nb * 16 + col;
#pragma unroll
        for (int rr = 0; rr < 4; ++rr) {
          int qrow = q0 + w * 16 + quad * 4 + rr;
          if (key > qrow) s[nb][rr] = -1e30f;
        }
      }
    }
    float tm[4];
#pragma unroll
    for (int rr = 0; rr < 4; ++rr)
      tm[rr] = fmaxf(fmaxf(s[0][rr], s[1][rr]), fmaxf(s[2][rr], s[3][rr]));
#pragma unroll
    for (int off = 1; off < 16; off <<= 1)
#pragma unroll
      for (int rr = 0; rr < 4; ++rr)
        tm[rr] = fmaxf(tm[rr], __shfl_xor(tm[rr], off));
    float alpha[4], rs[4];
#pragma unroll
    for (int rr = 0; rr < 4; ++rr) {
      float mn = fmaxf(mrow[rr], tm[rr]);
      alpha[rr] = __expf(mrow[rr] - mn);
      mrow[rr] = mn;
      rs[rr] = 0.f;
    }
#pragma unroll
    for (int nb = 0; nb < 4; ++nb)
#pragma unroll
      for (int rr = 0; rr < 4; ++rr) {
        float ev = __expf(s[nb][rr] - mrow[rr]);
        rs[rr] += ev;
        ps[w][(quad * 4 + rr) * 72 + nb * 16 + col] = f2b(ev);
      }
#pragma unroll
    for (int off = 1; off < 16; off <<= 1)
#pragma unroll
      for (int rr = 0; rr < 4; ++rr)
        rs[rr] += __shfl_xor(rs[rr], off);
#pragma unroll
    for (int rr = 0; rr < 4; ++rr) lrow[rr] = lrow[rr] * alpha[rr] + rs[rr];
#pragma unroll
    for (int nb = 0; nb < 4; ++nb)
#pragma unroll
      for (int rr = 0; rr < 4; ++rr) acc[nb][rr] *= alpha[rr];

    bf16x8 pa0 = *(bf16x8*)&ps[w][col * 72 + quad * 8];
    bf16x8 pa1 = *(bf16x8*)&ps[w][col * 72 + 32 + quad * 8];
#pragma unroll
    for (int nb = 0; nb < 4; ++nb) {
      int d = nb * 16 + col;
      int sw = (d & 7) << 3;
      bf16x8 vb0 = *(bf16x8*)&vst[d * 64 + ((quad * 8) ^ sw)];
      bf16x8 vb1 = *(bf16x8*)&vst[d * 64 + ((32 + quad * 8) ^ sw)];
      acc[nb] = __builtin_amdgcn_mfma_f32_16x16x32_bf16(pa0, vb0, acc[nb], 0, 0, 0);
      acc[nb] = __builtin_amdgcn_mfma_f32_16x16x32_bf16(pa1, vb1, acc[nb], 0, 0, 0);
    }
  }
#pragma unroll
  for (int rr = 0; rr < 4; ++rr) {
    float inv = 1.f / lrow[rr];
    int qrow = q0 + w * 16 + quad * 4 + rr;
    size_t base = (size_t)(b * QS + qrow) * HID_ + h * 64;
#pragma unroll
    for (int nb = 0; nb < 4; ++nb)
      ctx[base + nb * 16 + col] = f2b(acc[nb][rr] * inv);
  }
}

// ---------------- host ----------------
extern "C" void kernel_launch(void* const* d_in, const int* in_sizes, int n_in,
                              void* d_out, int out_size, void* d_ws, size_t ws_size,
                              hipStream_t stream) {
  (void)in_sizes; (void)n_in; (void)out_size; (void)ws_size;
  const float* hs_f = (const float*)d_in[0];
  const float* kb_f = (const float*)d_in[1];
  const float* Wq   = (const float*)d_in[2];
  const float* Wk   = (const float*)d_in[3];
  const float* Wv   = (const float*)d_in[4];
  const float* Wo   = (const float*)d_in[5];
  const float* Wqn  = (const float*)d_in[6];
  const float* Wkbk = (const float*)d_in[7];
  const float* Wkbv = (const float*)d_in[8];
  const float* cosT = (const float*)d_in[9];
  const float* sinT = (const float*)d_in[10];
  const int*   pid  = (const int*)d_in[12];
  float* out = (float*)d_out;

  char* p = (char*)d_ws;
  u16* WT    = (u16*)p; p += (size_t)FS * 2048 * 2;       // 20 MB weight arena (reused)
  u16* fused = (u16*)p; p += (size_t)B_ * QS * FS * 2;    // 20 MB q|k|v|kbq
  u16* hs_b  = (u16*)p; p += (size_t)B_ * QS * HID_ * 2;  // 8 MB (ctx aliases later)
  u16* kb_b  = (u16*)p; p += (size_t)B_ * KBN_ * HID_ * 2;// 4 MB (v_t/kb_t alias later)
  u16* kbf   = (u16*)p; p += (size_t)B_ * KBN_ * 1024 * 2;// 2 MB kbk|kbv
  double* hssum_ws = (double*)p; p += (size_t)B_ * HID_ * 8;
  double* S_ws     = (double*)p; p += (size_t)B_ * 512 * 8;
  double* U_ws     = (double*)p; p += (size_t)B_ * HID_ * 8;
  float*  sel_ws   = (float*)p;  p += (size_t)B_ * KBN_ * 4;
  int*    idx_ws   = (int*)p;    p += (size_t)B_ * TOPK_ * 4 + 4;
  double* partH    = (double*)p; p += (size_t)64 * B_ * HID_ * 8;
  double* partS    = (double*)p; p += (size_t)128 * B_ * 512 * 8;
  double* partU    = (double*)p; p += (size_t)4 * B_ * HID_ * 8;
  double* partSel  = (double*)p; p += (size_t)8 * B_ * KBN_ * 8;
  // aliases (lifetimes disjoint, stream-ordered):
  u16* ctx_ws = hs_b;                       // hs_b dead after fused GEMM
  u16* v_t    = kb_b;                       // kb_b dead after kb GEMM
  u16* kb_t   = kb_b + (size_t)B_ * 8 * 64 * 1024;

  dim3 blk(256);
  // casts
  cast_f2b<<<dim3((B_ * QS * HID_ / 4 + 255) / 256), blk, 0, stream>>>(hs_f, hs_b, B_ * QS * HID_ / 4);
  cast_f2b<<<dim3((B_ * KBN_ * HID_ / 4 + 255) / 256), blk, 0, stream>>>(kb_f, kb_b, B_ * KBN_ * HID_ / 4);
  // fused projection weights -> arena rows [q|k|v|kbq]
  transpose_cast_k<<<dim3(64, 64), blk, 0, stream>>>(Wq,  WT,                        2048, 2048);
  transpose_cast_k<<<dim3(16, 64), blk, 0, stream>>>(Wk,  WT + (size_t)2048 * 2048, 2048, 512);
  transpose_cast_k<<<dim3(16, 64), blk, 0, stream>>>(Wv,  WT + (size_t)2560 * 2048, 2048, 512);
  transpose_cast_k<<<dim3(64, 64), blk, 0, stream>>>(Wqn, WT + (size_t)3072 * 2048, 2048, 2048);
  gemm_nt2<false><<<dim3(FS / 128, 16), blk, 0, stream>>>(hs_b, WT, fused, 2048, FS, 2048, FS);
  // kb projection weights -> arena rows [kbk|kbv]
  transpose_cast_k<<<dim3(16, 64), blk, 0, stream>>>(Wkbk, WT,                       2048, 512);
  transpose_cast_k<<<dim3(16, 64), blk, 0, stream>>>(Wkbv, WT + (size_t)512 * 2048,  2048, 512);
  gemm_nt2<false><<<dim3(8, 8), blk, 0, stream>>>(kb_b, WT, kbf, 1024, 1024, 2048, 1024);
  // RoPE on q (offset 0) and k (offset 2048) inside fused
  rope_k<<<dim3((B_ * QS * NH_ * 32) / 256), blk, 0, stream>>>(fused, FS, cosT, sinT, pid, NH_, B_ * QS * NH_ * 32);
  rope_k<<<dim3((B_ * QS * NKV_ * 32) / 256), blk, 0, stream>>>(fused + 2048, FS, cosT, sinT, pid, NKV_, B_ * QS * NKV_ * 32);
  // selection path
  hssum_part_k<<<dim3(64, B_), blk, 0, stream>>>(hs_f, partH);
  red_d_k<<<dim3((B_ * HID_ + 255) / 256), blk, 0, stream>>>(partH, hssum_ws, 64, B_ * HID_);
  selS_part_k<<<dim3(128, B_), dim3(512), 0, stream>>>(hssum_ws, Wqn, partS);
  red_d_k<<<dim3((B_ * 512 + 255) / 256), blk, 0, stream>>>(partS, S_ws, 128, B_ * 512);
  selU_part_k<<<dim3(4, B_ * 8), blk, 0, stream>>>(S_ws, Wkbk, partU);
  red_d_k<<<dim3((B_ * HID_ + 255) / 256), blk, 0, stream>>>(partU, U_ws, 4, B_ * HID_);
  self_part_k<<<dim3(2, 8, B_), blk, 0, stream>>>(U_ws, kb_f, partSel);
  red_f_k<<<dim3((B_ * KBN_ + 255) / 256), blk, 0, stream>>>(partSel, sel_ws, 8, B_ * KBN_);
  topk_k<<<dim3(B_), dim3(64), 0, stream>>>(sel_ws, idx_ws);
  // V transpose + top-k V gather (kb_b region now free)
  vtrans_k<<<dim3(16, B_ * 8), blk, 0, stream>>>(fused, v_t);
  kbgather_k<<<dim3(B_ * 8), blk, 0, stream>>>(kbf, idx_ws, kb_t);
  // attention (writes ctx = hs_b alias)
  attn_mfma_k<<<dim3(QS / 64, NH_, B_), blk, 0, stream>>>(fused, kbf, v_t, kb_t, idx_ws, ctx_ws);
  // output projection
  transpose_cast_k<<<dim3(64, 64), blk, 0, stream>>>(Wo, WT, 2048, 2048);
  gemm_nt2<true><<<dim3(16, 16), blk, 0, stream>>>(ctx_ws, WT, out, 2048, 2048, 2048, 2048);
}